// Round 14
// baseline (360.408 us; speedup 1.0000x reference)
//
#include <hip/hip_runtime.h>
#include <hip/hip_bf16.h>

// Problem constants
#define B_   2
#define S_   2048
#define DIM_ 2048
#define NH   16
#define NKV  4
#define HD   128
#define QKVN 3072   // fused projection width: 2048 (Q) + 512 (K) + 512 (V)

typedef __attribute__((ext_vector_type(8)))  short  sv8;   // 8 x bf16 (MFMA operand)
typedef __attribute__((ext_vector_type(8)))  ushort usv8;
typedef __attribute__((ext_vector_type(4)))  float  fv4;
typedef __attribute__((ext_vector_type(16))) float  fv16;

__device__ __forceinline__ float fast_exp2(float x) {
  return __builtin_amdgcn_exp2f(x);   // v_exp_f32 (base-2)
}

__device__ __forceinline__ ushort f2bf(float f) {
  __hip_bfloat16 h = __float2bfloat16(f);
  union { __hip_bfloat16 h; ushort u; } c; c.h = h; return c.u;
}
__device__ __forceinline__ float bf2f(ushort u) {
  union { unsigned int i; float f; } c; c.i = ((unsigned)u) << 16; return c.f;
}

// pack two f32 -> two bf16 in one u32 (NOTE: possibly RTZ — use only for
// MFMA operands (P fragments), never for output-path rounding)
__device__ __forceinline__ unsigned int cvtpk(float lo, float hi) {
  unsigned int r;
  asm("v_cvt_pk_bf16_f32 %0, %1, %2" : "=v"(r) : "v"(lo), "v"(hi));
  return r;
}
// exchange with partner lane (lane ^ 32)
__device__ __forceinline__ unsigned int xhalf(unsigned int x) {
  return (unsigned int)__shfl_xor((int)x, 32, 64);
}

// tree reductions over a 16-vector (depth 5, ILP-friendly)
__device__ __forceinline__ float tmax16(const fv16& v) {
  float a = fmaxf(fmaxf(v[0], v[1]),  fmaxf(v[2], v[3]));
  float b = fmaxf(fmaxf(v[4], v[5]),  fmaxf(v[6], v[7]));
  float c = fmaxf(fmaxf(v[8], v[9]),  fmaxf(v[10], v[11]));
  float d = fmaxf(fmaxf(v[12], v[13]), fmaxf(v[14], v[15]));
  return fmaxf(fmaxf(a, b), fmaxf(c, d));
}
__device__ __forceinline__ float tsum16(const fv16& v) {
  float a = (v[0] + v[1]) + (v[2] + v[3]);
  float b = (v[4] + v[5]) + (v[6] + v[7]);
  float c = (v[8] + v[9]) + (v[10] + v[11]);
  float d = (v[12] + v[13]) + (v[14] + v[15]);
  return (a + b) + (c + d);
}

// async global->LDS, 16B per lane; LDS dest is wave-uniform base (HW adds lane*16).
__device__ __forceinline__ void async16(const void* g, void* l) {
  __builtin_amdgcn_global_load_lds(
      (const __attribute__((address_space(1))) unsigned int*)g,
      (__attribute__((address_space(3))) unsigned int*)l, 16, 0, 0);
}

// ---------------- f32 -> bf16 convert (x) ----------------
__global__ void cvt_kernel(const float* __restrict__ in, ushort* __restrict__ out, int n) {
  int i = (blockIdx.x * 256 + threadIdx.x) * 4;
  if (i >= n) return;
  fv4 v = *(const fv4*)(in + i);
  ushort4 o;
  o.x = f2bf(v[0]); o.y = f2bf(v[1]); o.z = f2bf(v[2]); o.w = f2bf(v[3]);
  *(ushort4*)(out + i) = o;
}

// ---------------- fused weight convert: wq|wk|wv -> wqkvb, wo -> wob ----------------
__global__ void cvtw_kernel(const float* __restrict__ wq, const float* __restrict__ wk,
                            const float* __restrict__ wv, const float* __restrict__ wo,
                            ushort* __restrict__ wqkvb, ushort* __restrict__ wob) {
  const int NQ = 2048 * 2048, NK = 512 * 2048;
  int i = (blockIdx.x * 256 + threadIdx.x) * 4;   // ranges are 1024-aligned: no straddle
  const float* src; ushort* dst;
  if (i < NQ)               { src = wq + i;                 dst = wqkvb + i; }
  else if (i < NQ + NK)     { src = wk + (i - NQ);          dst = wqkvb + i; }
  else if (i < NQ + 2 * NK) { src = wv + (i - NQ - NK);     dst = wqkvb + i; }
  else                      { int j = i - (NQ + 2 * NK); src = wo + j; dst = wob + j; }
  fv4 v = *(const fv4*)src;
  ushort4 o;
  o.x = f2bf(v[0]); o.y = f2bf(v[1]); o.z = f2bf(v[2]); o.w = f2bf(v[3]);
  *(ushort4*)dst = o;
}

// ---------------- fused RoPE Q+K, relayout to (B, heads, S, HD) ----------------
__global__ void rope2_kernel(const ushort* __restrict__ qkv, const float* __restrict__ fc,
                             const float* __restrict__ fs, ushort* __restrict__ qr,
                             ushort* __restrict__ kr, float qscale) {
  int t = blockIdx.x * 256 + threadIdx.x;   // B*S*20*16 threads, 8 elems each
  int grp = t & 15;
  int u   = t >> 4;
  int h2  = u % 20;
  int s   = (u / 20) % S_;
  int b   = u / (20 * S_);
  bool isQ  = h2 < 16;
  int h     = isQ ? h2 : h2 - 16;
  int heads = isQ ? NH : NKV;
  float scale = isQ ? qscale : 1.0f;
  const ushort* src = qkv + (size_t)(b * S_ + s) * QKVN + (isQ ? 0 : 2048) + h * HD + grp * 8;
  sv8 v = *(const sv8*)src;
  fv4 c  = *(const fv4*)(fc + s * 64 + grp * 4);
  fv4 sn = *(const fv4*)(fs + s * 64 + grp * 4);
  sv8 o;
#pragma unroll
  for (int p = 0; p < 4; ++p) {
    float re = bf2f((ushort)v[2 * p]);
    float im = bf2f((ushort)v[2 * p + 1]);
    float orr = (re * c[p] - im * sn[p]) * scale;
    float oi  = (re * sn[p] + im * c[p]) * scale;
    o[2 * p]     = (short)f2bf(orr);
    o[2 * p + 1] = (short)f2bf(oi);
  }
  ushort* dst = (isQ ? qr : kr) + ((size_t)(b * heads + h) * S_ + s) * HD + grp * 8;
  *(sv8*)dst = o;
}

// ---------------- V transpose: rows of fused qkv -> (B,KVH,HD,S) ----------------
__global__ __launch_bounds__(256) void vtrans_kernel(const ushort* __restrict__ vraw,
                                                     ushort* __restrict__ vt, int rowstride) {
  __shared__ ushort tile[128][136];
  int blk = blockIdx.x;            // (b*NKV+kv)*16 + st
  int st  = blk & 15;
  int kvb = blk >> 4;
  int kv  = kvb & 3;
  int b   = kvb >> 2;
  int s0  = st << 7;
#pragma unroll
  for (int it = 0; it < 8; ++it) {
    int t = it * 256 + threadIdx.x;
    int srow = t >> 4;
    int d8 = (t & 15) * 8;
    usv8 v = *(const usv8*)(vraw + (size_t)(b * S_ + s0 + srow) * rowstride + kv * HD + d8);
#pragma unroll
    for (int j = 0; j < 8; ++j) tile[d8 + j][srow] = v[j];
  }
  __syncthreads();
#pragma unroll
  for (int it = 0; it < 8; ++it) {
    int t = it * 256 + threadIdx.x;
    int d = t >> 4;
    int s8 = (t & 15) * 8;
    usv8 o;
#pragma unroll
    for (int j = 0; j < 8; ++j) o[j] = tile[d][s8 + j];
    *(usv8*)(vt + ((size_t)(b * NKV + kv) * HD + d) * S_ + s0 + s8) = o;
  }
}

// ---------------- 2-phase 256x192 GEMM (QKV): 256 blocks = 1/CU ---------------- (r12)
template <typename OutT>
__global__ __launch_bounds__(512) void gemm192(const ushort* __restrict__ A,
                                               const ushort* __restrict__ Bm,
                                               OutT* __restrict__ C,
                                               int M, int N, int K) {
  __shared__ __align__(16) ushort SM[57344];   // 112KB
  int nb = N / 192;
  int bx = blockIdx.x % nb, by = blockIdx.x / nb;
  int m0 = by << 8;
  int n0 = bx * 192;
  int tid = threadIdx.x;
  int lane = tid & 63, w = tid >> 6;
  int l15 = lane & 15, lg = lane >> 4;
  int wm = (w >> 2) * 128;
  int wn = (w & 3) * 48;
  int pA = w >> 2;

  int srow = tid >> 3;
  int cb   = ((tid & 7) * 16) ^ ((srow & 7) << 4);
  const ushort* sA = A  + (size_t)(m0 + srow) * K + (cb >> 1);
  const ushort* sB = Bm + (size_t)(n0 + srow) * K + (cb >> 1);
  size_t rstep = (size_t)64 * K;
  int nkt = K >> 6;

  auto STG_A = [&](int t, int db) {
    ushort* base = SM + db * 28672 + (w << 9);
    const ushort* a0 = sA + (size_t)t * 64;
    async16(a0,             base);
    async16(a0 + rstep,     base + 4096);
    async16(a0 + 2 * rstep, base + 8192);
    async16(a0 + 3 * rstep, base + 12288);
  };
  auto STG_B = [&](int t, int db) {
    ushort* base = SM + db * 28672 + 16384 + (w << 9);
    const ushort* b0 = sB + (size_t)t * 64;
    async16(b0,             base);
    async16(b0 + rstep,     base + 4096);
    async16(b0 + 2 * rstep, base + 8192);
  };

  fv4 acc[8][3] = {};
  sv8 alo[4][2], ahi[4][2], b01[2][2], b2v[2];

  STG_A(0, 0); STG_B(0, 0);
  { int t1 = nkt > 1 ? 1 : 0; STG_A(t1, 1); STG_B(t1, 1); }
  asm volatile("s_waitcnt vmcnt(7)");
  __builtin_amdgcn_s_barrier();

  for (int t = 0; t < nkt; ++t) {
    int db = t & 1;
    int t2 = t + 2 < nkt ? t + 2 : nkt - 1;
    const char* Ab = (const char*)(SM + db * 28672) + pA * 16384;
    const char* Bb = (const char*)(SM + db * 28672) + 32768;

    // ---- P1: read ALL A (16) + ALL B (6); 32 MFMA (A x {j0,j1}) ----
#pragma unroll
    for (int m = 0; m < 4; ++m)
#pragma unroll
      for (int kk = 0; kk < 2; ++kk) {
        int row = m * 16 + l15;
        alo[m][kk] = *(const sv8*)(Ab + row * 128 + ((kk * 64 + lg * 16) ^ ((row & 7) << 4)));
      }
#pragma unroll
    for (int m = 0; m < 4; ++m)
#pragma unroll
      for (int kk = 0; kk < 2; ++kk) {
        int row = 64 + m * 16 + l15;
        ahi[m][kk] = *(const sv8*)(Ab + row * 128 + ((kk * 64 + lg * 16) ^ ((row & 7) << 4)));
      }
#pragma unroll
    for (int j = 0; j < 2; ++j)
#pragma unroll
      for (int kk = 0; kk < 2; ++kk) {
        int row = wn + j * 16 + l15;
        b01[j][kk] = *(const sv8*)(Bb + row * 128 + ((kk * 64 + lg * 16) ^ ((row & 7) << 4)));
      }
#pragma unroll
    for (int kk = 0; kk < 2; ++kk) {
      int row = wn + 32 + l15;
      b2v[kk] = *(const sv8*)(Bb + row * 128 + ((kk * 64 + lg * 16) ^ ((row & 7) << 4)));
    }
    __builtin_amdgcn_s_barrier();
    asm volatile("s_waitcnt lgkmcnt(0)");
    __builtin_amdgcn_s_setprio(1);
#pragma unroll
    for (int m = 0; m < 4; ++m)
#pragma unroll
      for (int j = 0; j < 2; ++j)
#pragma unroll
        for (int kk = 0; kk < 2; ++kk) {
          acc[m][j]     = __builtin_amdgcn_mfma_f32_16x16x32_bf16(alo[m][kk], b01[j][kk], acc[m][j], 0, 0, 0);
          acc[m + 4][j] = __builtin_amdgcn_mfma_f32_16x16x32_bf16(ahi[m][kk], b01[j][kk], acc[m + 4][j], 0, 0, 0);
        }
    __builtin_amdgcn_s_setprio(0);
    __builtin_amdgcn_s_barrier();

    // ---- P2: stage T+2 (7 loads); vmcnt(7) -> T+1 landed; 16 MFMA (A x j2) ----
    STG_A(t2, db);
    STG_B(t2, db);
    asm volatile("s_waitcnt vmcnt(7)");
    __builtin_amdgcn_s_barrier();
    __builtin_amdgcn_s_setprio(1);
#pragma unroll
    for (int m = 0; m < 4; ++m)
#pragma unroll
      for (int kk = 0; kk < 2; ++kk) {
        acc[m][2]     = __builtin_amdgcn_mfma_f32_16x16x32_bf16(alo[m][kk], b2v[kk], acc[m][2], 0, 0, 0);
        acc[m + 4][2] = __builtin_amdgcn_mfma_f32_16x16x32_bf16(ahi[m][kk], b2v[kk], acc[m + 4][2], 0, 0, 0);
      }
    __builtin_amdgcn_s_setprio(0);
    __builtin_amdgcn_s_barrier();
  }

  asm volatile("s_waitcnt vmcnt(0)");
#pragma unroll
  for (int m = 0; m < 8; ++m)
#pragma unroll
    for (int j = 0; j < 3; ++j)
#pragma unroll
      for (int r = 0; r < 4; ++r) {
        int row = m0 + wm + m * 16 + lg * 4 + r;
        int col = n0 + wn + j * 16 + l15;
        if constexpr (sizeof(OutT) == 2) C[(size_t)row * N + col] = (OutT)f2bf(acc[m][j][r]);
        else                             C[(size_t)row * N + col] = (OutT)acc[m][j][r];
      }
}

// ---------------- 2-phase 256x128 GEMM (o-proj): 16 MFMA per phase --------------- (unchanged)
template <typename OutT>
__global__ __launch_bounds__(512) void gemmOP(const ushort* __restrict__ A,
                                              const ushort* __restrict__ Bm,
                                              OutT* __restrict__ C,
                                              int M, int N, int K) {
  __shared__ __align__(16) ushort SM[49152];   // 96KB
  int nb = N >> 7;
  int bx = blockIdx.x % nb, by = blockIdx.x / nb;
  int m0 = by << 8, n0 = bx << 7;
  int tid = threadIdx.x;
  int lane = tid & 63, w = tid >> 6;
  int l15 = lane & 15, lg = lane >> 4;
  int wm = (w >> 2) * 128;
  int wn = (w & 3) * 32;
  int pA = (w >> 2);

  int srow = tid >> 3;
  int cb   = ((tid & 7) * 16) ^ ((srow & 7) << 4);
  const ushort* sA0 = A  + (size_t)(m0 + srow) * K + (cb >> 1);
  const ushort* sB0 = Bm + (size_t)(n0 + srow) * K + (cb >> 1);
  const ushort* srcs[3] = { sA0, sA0 + (size_t)128 * K, sB0 };
  size_t rstep = (size_t)64 * K;

  int nkt = K >> 6;

  auto STG = [&](int part, int t, int db) {
    ushort* d0 = SM + db * 24576 + part * 8192 + (w << 9);
    const ushort* s0 = srcs[part] + t * 64;
    async16(s0, d0);
    async16(s0 + rstep, d0 + 4096);
  };

  fv4 acc[8][2] = {};
  sv8 a[8][2], b[2][2];

#pragma unroll
  for (int p = 0; p < 3; ++p) STG(p, 0, 0);
  {
    int t1 = 1 < nkt ? 1 : 0;
#pragma unroll
    for (int p = 0; p < 3; ++p) STG(p, t1, 1);
  }
  asm volatile("s_waitcnt vmcnt(6)");
  __builtin_amdgcn_s_barrier();

  for (int t = 0; t < nkt; ++t) {
    int db = t & 1;
    int t2 = t + 2 < nkt ? t + 2 : nkt - 1;
    const char* Ab = (const char*)SM + db * 49152 + pA * 16384;
    const char* Bb = (const char*)SM + db * 49152 + 32768;

    // ---- P1: read all A (16) + B j0,j1 (4); MFMA A-lo x {j0,j1} ----
#pragma unroll
    for (int m = 0; m < 8; ++m)
#pragma unroll
      for (int kk = 0; kk < 2; ++kk) {
        int row = m * 16 + l15;
        a[m][kk] = *(const sv8*)(Ab + row * 128 + ((kk * 64 + lg * 16) ^ ((row & 7) << 4)));
      }
#pragma unroll
    for (int j = 0; j < 2; ++j)
#pragma unroll
      for (int kk = 0; kk < 2; ++kk) {
        int row = wn + j * 16 + l15;
        b[j][kk] = *(const sv8*)(Bb + row * 128 + ((kk * 64 + lg * 16) ^ ((row & 7) << 4)));
      }
    __builtin_amdgcn_s_barrier();
    asm volatile("s_waitcnt lgkmcnt(0)");
    __builtin_amdgcn_s_setprio(1);
#pragma unroll
    for (int m = 0; m < 4; ++m)
#pragma unroll
      for (int j = 0; j < 2; ++j)
#pragma unroll
        for (int kk = 0; kk < 2; ++kk)
          acc[m][j] = __builtin_amdgcn_mfma_f32_16x16x32_bf16(a[m][kk], b[j][kk], acc[m][j], 0, 0, 0);
    __builtin_amdgcn_s_setprio(0);
    __builtin_amdgcn_s_barrier();

    // ---- P2: stage T+2 (6 loads); vmcnt(6) -> T+1 landed; MFMA A-hi x {j0,j1} ----
    STG(0, t2, db);
    STG(1, t2, db);
    STG(2, t2, db);
    asm volatile("s_waitcnt vmcnt(6)");
    __builtin_amdgcn_s_barrier();
    __builtin_amdgcn_s_setprio(1);
#pragma unroll
    for (int m = 0; m < 4; ++m)
#pragma unroll
      for (int j = 0; j < 2; ++j)
#pragma unroll
        for (int kk = 0; kk < 2; ++kk)
          acc[m + 4][j] = __builtin_amdgcn_mfma_f32_16x16x32_bf16(a[m + 4][kk], b[j][kk], acc[m + 4][j], 0, 0, 0);
    __builtin_amdgcn_s_setprio(0);
    __builtin_amdgcn_s_barrier();
  }

  asm volatile("s_waitcnt vmcnt(0)");
#pragma unroll
  for (int m = 0; m < 8; ++m)
#pragma unroll
    for (int j = 0; j < 2; ++j)
#pragma unroll
      for (int r = 0; r < 4; ++r) {
        int row = m0 + wm + m * 16 + lg * 4 + r;
        int col = n0 + wn + j * 16 + l15;
        if constexpr (sizeof(OutT) == 2) C[(size_t)row * N + col] = (OutT)f2bf(acc[m][j][r]);
        else                             C[(size_t)row * N + col] = (OutT)acc[m][j][r];
      }
}

// ---------------- Flash attention (causal, GQA), hybrid split-K ----------------
// 256 thr (4 waves x 32 q-rows), KVBLK=64, dbuf K/V (64KB LDS) -> 2 blocks/CU.
// bid < 512: split half (qt 8..15, heavy-first), chain = qt+1 <= 16.
//            f32 partials to ws; merge by second-arriving block (symmetric).
// bid >= 512: single block (qt 0..7), chain = 2qt+2 <= 16, direct write.
__global__ __launch_bounds__(256, 2) void attn_kernel(const ushort* __restrict__ Q,
                                                      const ushort* __restrict__ Kr,
                                                      const ushort* __restrict__ Vt,
                                                      ushort* __restrict__ O,
                                                      float* __restrict__ pOf,
                                                      float* __restrict__ pML,
                                                      int* __restrict__ cnt) {
  __shared__ __align__(16) ushort SMEM[32768];   // 64KB: K[2][8192], V[2][8192]
  __shared__ int oldS;

  int bid = blockIdx.x;
  bool split = bid < 512;
  int hf, key, qt, bh;
  if (split) {
    hf  = bid & 1;
    key = bid >> 1;                // [0,256): (b,h,qt>=8)
    bh  = key & 31;
    qt  = 15 - (key >> 5);         // 15..8, heavy-first
  } else {
    hf  = 0;
    key = 0;
    int s = bid - 512;             // [0,256)
    bh  = s & 31;
    qt  = 7 - (s >> 5);            // 7..0, heavy-first
  }
  int h   = bh & 15;
  int b   = bh >> 4;
  int kv  = h >> 2;
  int tid = threadIdx.x;
  int lane = tid & 63, w = tid >> 6;    // 4 waves
  int l31 = lane & 31, hh = lane >> 5;
  int q0 = qt << 7;
  int qrow_w = q0 + w * 32;
  int myq    = qrow_w + l31;
  int nj     = split ? (qt + 1) : (2 * qt + 2);
  int ktbase = split ? hf * nj : 0;

  const ushort* Qbase = Q  + (size_t)(b * NH  + h ) * S_ * HD;
  const ushort* Kbase = Kr + (size_t)(b * NKV + kv) * S_ * HD;
  const ushort* Vbase = Vt + (size_t)(b * NKV + kv) * HD * S_;

  const ushort* kSrc[4]; ushort* kDst[2][4];
  const ushort* vSrc[4]; ushort* vDst[2][4];
#pragma unroll
  for (int it = 0; it < 4; ++it) {
    int lin = it * 4096 + w * 1024 + lane * 16;
    { int row = lin >> 8; int cbv = (lin & 255) ^ ((row & 15) << 4);
      kSrc[it] = Kbase + (size_t)row * HD + (cbv >> 1); }
    { int row = lin >> 8; int cp = lin & 255; int cl = cp ^ ((row & 15) << 4);
      int d = row + ((cl >> 7) << 6);
      int koff = (cl & 127) >> 1;
      vSrc[it] = Vbase + (size_t)d * S_ + koff; }
#pragma unroll
    for (int buf = 0; buf < 2; ++buf) {
      kDst[buf][it] = SMEM + buf * 8192 + ((it * 4096 + w * 1024) >> 1);
      vDst[buf][it] = SMEM + 16384 + buf * 8192 + ((it * 4096 + w * 1024) >> 1);
    }
  }

  sv8 qf[8];
#pragma unroll
  for (int kk = 0; kk < 8; ++kk)
    qf[kk] = *(const sv8*)(Qbase + (size_t)myq * HD + kk * 16 + hh * 8);

  fv16 oacc[4] = {};
  float mrun = -1e30f, lrun = 0.f;

  // prologue: tile 0 of this range into buf 0
  {
    size_t k0 = (size_t)ktbase << 6;
#pragma unroll
    for (int it = 0; it < 4; ++it) async16(kSrc[it] + k0 * HD, kDst[0][it]);
#pragma unroll
    for (int it = 0; it < 4; ++it) async16(vSrc[it] + k0,      vDst[0][it]);
  }

  for (int j = 0; j < nj; ++j) {
    int cur = j & 1, nxt = cur ^ 1;
    __syncthreads();   // drains vmcnt -> buf[cur] done; all waves done with buf[nxt]
    if (j + 1 < nj) {
      size_t k0n = (size_t)(ktbase + j + 1) << 6;
#pragma unroll
      for (int it = 0; it < 4; ++it) async16(kSrc[it] + k0n * HD, kDst[nxt][it]);
#pragma unroll
      for (int it = 0; it < 4; ++it) async16(vSrc[it] + k0n,      vDst[nxt][it]);
    }
    const char* KsC = (const char*)(SMEM + cur * 8192);
    const char* VsC = (const char*)(SMEM + 16384 + cur * 8192);
    int k0 = (ktbase + j) << 6;

    fv16 sacc[2] = {};
    __builtin_amdgcn_s_setprio(1);
#pragma unroll
    for (int kk = 0; kk < 8; ++kk) {
      int cbq = kk * 32 + hh * 16;
      int r0 = l31, r1 = 32 + l31;
      sv8 kf0 = *(const sv8*)(KsC + r0 * 256 + (cbq ^ ((r0 & 15) << 4)));
      sv8 kf1 = *(const sv8*)(KsC + r1 * 256 + (cbq ^ ((r1 & 15) << 4)));
      sacc[0] = __builtin_amdgcn_mfma_f32_32x32x16_bf16(kf0, qf[kk], sacc[0], 0, 0, 0);
      sacc[1] = __builtin_amdgcn_mfma_f32_32x32x16_bf16(kf1, qf[kk], sacc[1], 0, 0, 0);
    }
    __builtin_amdgcn_s_setprio(0);

    if (k0 + 63 > qrow_w) {
      int thr = myq - k0 - 4 * hh;
#pragma unroll
      for (int t = 0; t < 2; ++t)
#pragma unroll
        for (int r = 0; r < 16; ++r) {
          int kp = t * 32 + (r & 3) + 8 * (r >> 2);
          if (kp > thr) sacc[t][r] = -1e38f;
        }
    }

    float tmax = fmaxf(tmax16(sacc[0]), tmax16(sacc[1]));
    tmax = fmaxf(tmax, __shfl_xor(tmax, 32, 64));

    if (__any(tmax > mrun + 8.0f)) {
      float mnew = fmaxf(mrun, tmax);
      float esc  = fast_exp2(mrun - mnew);
      lrun *= esc;
      float er[16];
#pragma unroll
      for (int r = 0; r < 16; ++r) er[r] = __shfl(esc, (r & 3) + 8 * (r >> 2) + 4 * hh, 64);
#pragma unroll
      for (int d0 = 0; d0 < 4; ++d0)
#pragma unroll
        for (int r = 0; r < 16; ++r) oacc[d0][r] *= er[r];
      mrun = mnew;
    }

#pragma unroll
    for (int t = 0; t < 2; ++t)
#pragma unroll
      for (int r = 0; r < 16; ++r) sacc[t][r] = fast_exp2(sacc[t][r] - mrun);
    float psum = tsum16(sacc[0]) + tsum16(sacc[1]);
    psum += __shfl_xor(psum, 32, 64);
    lrun += psum;

    union Frag { unsigned int u[4]; sv8 v; } pa[4];
#pragma unroll
    for (int t = 0; t < 2; ++t)
#pragma unroll
      for (int half = 0; half < 2; ++half) {
        int cbq = half * 8;
        unsigned int a0 = cvtpk(sacc[t][cbq + 0], sacc[t][cbq + 1]);
        unsigned int a1 = cvtpk(sacc[t][cbq + 2], sacc[t][cbq + 3]);
        unsigned int b0 = cvtpk(sacc[t][cbq + 4], sacc[t][cbq + 5]);
        unsigned int b1 = cvtpk(sacc[t][cbq + 6], sacc[t][cbq + 7]);
        unsigned int a0p = xhalf(a0), a1p = xhalf(a1);
        unsigned int b0p = xhalf(b0), b1p = xhalf(b1);
        pa[2 * t + half].u[0] = hh ? b0p : a0;
        pa[2 * t + half].u[1] = hh ? b1p : a1;
        pa[2 * t + half].u[2] = hh ? b0  : a0p;
        pa[2 * t + half].u[3] = hh ? b1  : a1p;
      }

    __builtin_amdgcn_s_setprio(1);
#pragma unroll
    for (int ks = 0; ks < 4; ++ks) {
#pragma unroll
      for (int d0 = 0; d0 < 4; ++d0) {
        int d = d0 * 32 + l31;
        int row = d & 63;
        int cl = ((d >> 6) << 7) + ks * 32 + hh * 16;
        sv8 vf = *(const sv8*)(VsC + row * 256 + (cl ^ ((row & 15) << 4)));
        oacc[d0] = __builtin_amdgcn_mfma_f32_32x32x16_bf16(pa[ks].v, vf, oacc[d0], 0, 0, 0);
      }
    }
    __builtin_amdgcn_s_setprio(0);
  }

  if (!split) {
    // single block: normalize and write directly (r12 numerics)
    float inv = 1.0f / lrun;
    float ir[16];
#pragma unroll
    for (int r = 0; r < 16; ++r) ir[r] = __shfl(inv, (r & 3) + 8 * (r >> 2) + 4 * hh, 64);
#pragma unroll
    for (int r = 0; r < 16; ++r) {
      int q = qrow_w + (r & 3) + 8 * (r >> 2) + 4 * hh;
#pragma unroll
      for (int d0 = 0; d0 < 4; ++d0) {
        int d = d0 * 32 + l31;
        O[(size_t)(b * S_ + q) * DIM_ + h * HD + d] = f2bf(oacc[d0][r] * ir[r]);
      }
    }
    return;
  }

  // ---- split: write f32 partials (no extra rounding) ----
  {
    float* myO = pOf + ((size_t)key * 2 + hf) * 16384 + (size_t)tid * 64;
#pragma unroll
    for (int d0 = 0; d0 < 4; ++d0)
#pragma unroll
      for (int j2 = 0; j2 < 4; ++j2) {
        fv4 t;
        t[0] = oacc[d0][4 * j2 + 0]; t[1] = oacc[d0][4 * j2 + 1];
        t[2] = oacc[d0][4 * j2 + 2]; t[3] = oacc[d0][4 * j2 + 3];
        *(fv4*)(myO + d0 * 16 + 4 * j2) = t;
      }
    float* myML = pML + ((size_t)key * 2 + hf) * 512 + tid * 2;
    myML[0] = mrun;
    myML[1] = lrun;
  }
  __threadfence();
  __syncthreads();
  if (tid == 0) oldS = atomicAdd(&cnt[key], 1);
  __syncthreads();
  if (oldS == 0) return;           // first half done; second will merge
  __threadfence();

  // ---- merge (reads BOTH halves from ws -> order-independent result) ----
  const float* o0 = pOf + (size_t)key * 32768 + (size_t)tid * 64;
  const float* o1 = o0 + 16384;
  const float* ml0 = pML + (size_t)key * 1024 + tid * 2;
  const float* ml1 = ml0 + 512;
  float m0 = ml0[0], l0 = ml0[1];
  float m1 = ml1[0], l1 = ml1[1];
  float mm = fmaxf(m0, m1);
  float e0 = fast_exp2(m0 - mm), e1 = fast_exp2(m1 - mm);
  float linv = 1.0f / (l0 * e0 + l1 * e1);
  float f0 = e0 * linv, f1 = e1 * linv;
  float f0b[16], f1b[16];
#pragma unroll
  for (int r = 0; r < 16; ++r) {
    int ro = (r & 3) + 8 * (r >> 2) + 4 * hh;
    f0b[r] = __shfl(f0, ro, 64);
    f1b[r] = __shfl(f1, ro, 64);
  }
#pragma unroll
  for (int d0 = 0; d0 < 4; ++d0) {
#pragma unroll
    for (int j2 = 0; j2 < 4; ++j2) {
      fv4 x = *(const fv4*)(o0 + d0 * 16 + 4 * j2);
      fv4 y = *(const fv4*)(o1 + d0 * 16 + 4 * j2);
#pragma unroll
      for (int rr = 0; rr < 4; ++rr) {
        int r = 4 * j2 + rr;
        float val = x[rr] * f0b[r] + y[rr] * f1b[r];
        int q = qrow_w + (r & 3) + 8 * (r >> 2) + 4 * hh;
        int d = d0 * 32 + l31;
        O[(size_t)(b * S_ + q) * DIM_ + h * HD + d] = f2bf(val);
      }
    }
  }
}

// ---------------- host launcher ----------------
extern "C" void kernel_launch(void* const* d_in, const int* in_sizes, int n_in,
                              void* d_out, int out_size, void* d_ws, size_t ws_size,
                              hipStream_t stream) {
  const float* x  = (const float*)d_in[0];
  const float* wq = (const float*)d_in[1];
  const float* wk = (const float*)d_in[2];
  const float* wv = (const float*)d_in[3];
  const float* wo = (const float*)d_in[4];
  const float* fc = (const float*)d_in[5];
  const float* fs = (const float*)d_in[6];
  float* out = (float*)d_out;

  char* ws = (char*)d_ws;
  size_t off = 0;
  auto alloc = [&](size_t bytes) -> ushort* {
    ushort* p = (ushort*)(ws + off);
    off += (bytes + 255) & ~(size_t)255;
    return p;
  };
  // xb, wqkvb, qkvr placed FIRST: all dead by attention time; the attention
  // split-K f32 partials (34.6MB) overlay this 54.5MB region.
  ushort* xb    = alloc((size_t)B_ * S_ * DIM_ * 2);        // 16.8MB (dead after gemm192)
  ushort* wqkvb = alloc((size_t)QKVN * DIM_ * 2);           // 12.6MB (dead after gemm192)
  ushort* qkvr  = alloc((size_t)B_ * S_ * QKVN * 2);        // 25.2MB (dead after rope/vtrans)
  ushort* wob   = alloc((size_t)DIM_ * DIM_ * 2);           // 8MB   (live until gemmOP)
  ushort* qr    = alloc((size_t)B_ * S_ * DIM_ * 2);        // 16MB
  ushort* kr    = alloc((size_t)B_ * S_ * NKV * HD * 2);    // 4MB
  ushort* vtb   = alloc((size_t)B_ * S_ * NKV * HD * 2);    // 4MB
  ushort* obf   = alloc((size_t)B_ * S_ * DIM_ * 2);        // 16MB
  (void)ws_size; (void)n_in; (void)in_sizes; (void)out_size;

  // split-K partial buffers (f32) overlay the dead region
  float* pOf  = (float*)(ws + 0);           // 256*2*256*64*4B = 33,554,432 B
  float* pML  = (float*)(ws + 33554432);    // 256*2*256*2*4B  =  1,048,576 B
  int*   cntP = (int*)(ws + 34603008);      // 256*4B

  // converts: x, then all weights in one launch
  cvt_kernel<<<(B_ * S_ * DIM_) / 1024, 256, 0, stream>>>(x, xb, B_ * S_ * DIM_);
  cvtw_kernel<<<(2 * DIM_ * DIM_ + 2 * NKV * HD * DIM_) / 1024, 256, 0, stream>>>(
      wq, wk, wv, wo, wqkvb, wob);

  // fused QKV projection: [4096, 2048] x [3072, 2048]^T -> [4096, 3072] (2-phase 256x192)
  gemm192<ushort><<<(B_ * S_ / 256) * (QKVN / 192), 512, 0, stream>>>(xb, wqkvb, qkvr,
                                                                     B_ * S_, QKVN, DIM_);

  // fused rope Q+K; Q scale = 1/sqrt(128) * log2(e) (softmax runs in base 2)
  const float qscale = 0.08838834764831845f * 1.4426950408889634f;
  rope2_kernel<<<(B_ * S_ * 20 * 16) / 256, 256, 0, stream>>>(qkvr, fc, fs, qr, kr, qscale);
  vtrans_kernel<<<B_ * NKV * (S_ / 128), 256, 0, stream>>>(qkvr + 2560, vtb, QKVN);

  // attention: 768 blocks x 256 thr (512 split halves for qt>=8 + 256 singles)
  hipMemsetAsync(cntP, 0, 256 * sizeof(int), stream);
  attn_kernel<<<768, 256, 0, stream>>>(qr, kr, vtb, obf, pOf, pML, cntP);

  // output projection -> f32 d_out (2-phase 256x128 tiles, 256 blocks = 1/CU)
  gemmOP<float><<<(B_ * S_ / 256) * (DIM_ / 128), 512, 0, stream>>>(obf, wob, out, B_ * S_, DIM_, DIM_);
}

// Round 15
// 190.042 us; speedup vs baseline: 1.8965x; 1.8965x over previous
//
#include <hip/hip_runtime.h>
#include <hip/hip_bf16.h>

// Problem constants
#define B_   2
#define S_   2048
#define DIM_ 2048
#define NH   16
#define NKV  4
#define HD   128
#define QKVN 3072   // fused projection width: 2048 (Q) + 512 (K) + 512 (V)

typedef __attribute__((ext_vector_type(8)))  short  sv8;   // 8 x bf16 (MFMA operand)
typedef __attribute__((ext_vector_type(8)))  ushort usv8;
typedef __attribute__((ext_vector_type(4)))  float  fv4;
typedef __attribute__((ext_vector_type(16))) float  fv16;

__device__ __forceinline__ float fast_exp2(float x) {
  return __builtin_amdgcn_exp2f(x);   // v_exp_f32 (base-2)
}

__device__ __forceinline__ ushort f2bf(float f) {
  __hip_bfloat16 h = __float2bfloat16(f);
  union { __hip_bfloat16 h; ushort u; } c; c.h = h; return c.u;
}
__device__ __forceinline__ float bf2f(ushort u) {
  union { unsigned int i; float f; } c; c.i = ((unsigned)u) << 16; return c.f;
}

// pack two f32 -> two bf16 in one u32 (possibly RTZ — only for MFMA operands)
__device__ __forceinline__ unsigned int cvtpk(float lo, float hi) {
  unsigned int r;
  asm("v_cvt_pk_bf16_f32 %0, %1, %2" : "=v"(r) : "v"(lo), "v"(hi));
  return r;
}
// exchange with partner lane (lane ^ 32)
__device__ __forceinline__ unsigned int xhalf(unsigned int x) {
  return (unsigned int)__shfl_xor((int)x, 32, 64);
}

// tree reductions over a 16-vector (depth 5, ILP-friendly)
__device__ __forceinline__ float tmax16(const fv16& v) {
  float a = fmaxf(fmaxf(v[0], v[1]),  fmaxf(v[2], v[3]));
  float b = fmaxf(fmaxf(v[4], v[5]),  fmaxf(v[6], v[7]));
  float c = fmaxf(fmaxf(v[8], v[9]),  fmaxf(v[10], v[11]));
  float d = fmaxf(fmaxf(v[12], v[13]), fmaxf(v[14], v[15]));
  return fmaxf(fmaxf(a, b), fmaxf(c, d));
}
__device__ __forceinline__ float tsum16(const fv16& v) {
  float a = (v[0] + v[1]) + (v[2] + v[3]);
  float b = (v[4] + v[5]) + (v[6] + v[7]);
  float c = (v[8] + v[9]) + (v[10] + v[11]);
  float d = (v[12] + v[13]) + (v[14] + v[15]);
  return (a + b) + (c + d);
}

// async global->LDS, 16B per lane; LDS dest is wave-uniform base (HW adds lane*16).
__device__ __forceinline__ void async16(const void* g, void* l) {
  __builtin_amdgcn_global_load_lds(
      (const __attribute__((address_space(1))) unsigned int*)g,
      (__attribute__((address_space(3))) unsigned int*)l, 16, 0, 0);
}

// ---------------- fused f32->bf16 convert: x, then wq|wk|wv -> wqkvb, wo -> wob ----
__global__ void cvtall_kernel(const float* __restrict__ x,
                              const float* __restrict__ wq, const float* __restrict__ wk,
                              const float* __restrict__ wv, const float* __restrict__ wo,
                              ushort* __restrict__ xb,
                              ushort* __restrict__ wqkvb, ushort* __restrict__ wob) {
  const int NX = 2 * 2048 * 2048;                 // x elems
  const int NQ = 2048 * 2048, NK = 512 * 2048;    // weight ranges (1024-aligned)
  int i = (blockIdx.x * 256 + threadIdx.x) * 4;
  const float* src; ushort* dst;
  if (i < NX) { src = x + i; dst = xb + i; }
  else {
    int j = i - NX;
    if (j < NQ)               { src = wq + j;             dst = wqkvb + j; }
    else if (j < NQ + NK)     { src = wk + (j - NQ);      dst = wqkvb + j; }
    else if (j < NQ + 2 * NK) { src = wv + (j - NQ - NK); dst = wqkvb + j; }
    else                      { int k = j - (NQ + 2 * NK); src = wo + k; dst = wob + k; }
  }
  fv4 v = *(const fv4*)src;
  ushort4 o;
  o.x = f2bf(v[0]); o.y = f2bf(v[1]); o.z = f2bf(v[2]); o.w = f2bf(v[3]);
  *(ushort4*)dst = o;
}

// ---------------- fused prep: RoPE Q+K (blocks 0..5119) + V transpose (5120..5247) ----
// rope: relayout to (B, heads, S, HD), Q scaled by 1/sqrt(128)*log2(e).
// vtrans: qkv V columns -> (B,KVH,HD,S).
__global__ __launch_bounds__(256) void prep_kernel(const ushort* __restrict__ qkv,
                                                   const float* __restrict__ fc,
                                                   const float* __restrict__ fs,
                                                   ushort* __restrict__ qr,
                                                   ushort* __restrict__ kr,
                                                   ushort* __restrict__ vt,
                                                   float qscale) {
  __shared__ ushort tile[128][136];
  if (blockIdx.x < 5120) {
    // ---- RoPE path ----
    int t = blockIdx.x * 256 + threadIdx.x;   // B*S*20*16 threads, 8 elems each
    int grp = t & 15;
    int u   = t >> 4;
    int h2  = u % 20;
    int s   = (u / 20) % S_;
    int b   = u / (20 * S_);
    bool isQ  = h2 < 16;
    int h     = isQ ? h2 : h2 - 16;
    int heads = isQ ? NH : NKV;
    float scale = isQ ? qscale : 1.0f;
    const ushort* src = qkv + (size_t)(b * S_ + s) * QKVN + (isQ ? 0 : 2048) + h * HD + grp * 8;
    sv8 v = *(const sv8*)src;
    fv4 c  = *(const fv4*)(fc + s * 64 + grp * 4);
    fv4 sn = *(const fv4*)(fs + s * 64 + grp * 4);
    sv8 o;
#pragma unroll
    for (int p = 0; p < 4; ++p) {
      float re = bf2f((ushort)v[2 * p]);
      float im = bf2f((ushort)v[2 * p + 1]);
      float orr = (re * c[p] - im * sn[p]) * scale;
      float oi  = (re * sn[p] + im * c[p]) * scale;
      o[2 * p]     = (short)f2bf(orr);
      o[2 * p + 1] = (short)f2bf(oi);
    }
    ushort* dst = (isQ ? qr : kr) + ((size_t)(b * heads + h) * S_ + s) * HD + grp * 8;
    *(sv8*)dst = o;
  } else {
    // ---- V transpose path ----
    const ushort* vraw = qkv + 2560;
    int blk = blockIdx.x - 5120;     // (b*NKV+kv)*16 + st
    int st  = blk & 15;
    int kvb = blk >> 4;
    int kv  = kvb & 3;
    int b   = kvb >> 2;
    int s0  = st << 7;
#pragma unroll
    for (int it = 0; it < 8; ++it) {
      int t = it * 256 + threadIdx.x;
      int srow = t >> 4;
      int d8 = (t & 15) * 8;
      usv8 v = *(const usv8*)(vraw + (size_t)(b * S_ + s0 + srow) * QKVN + kv * HD + d8);
#pragma unroll
      for (int j = 0; j < 8; ++j) tile[d8 + j][srow] = v[j];
    }
    __syncthreads();
#pragma unroll
    for (int it = 0; it < 8; ++it) {
      int t = it * 256 + threadIdx.x;
      int d = t >> 4;
      int s8 = (t & 15) * 8;
      usv8 o;
#pragma unroll
      for (int j = 0; j < 8; ++j) o[j] = tile[d][s8 + j];
      *(usv8*)(vt + ((size_t)(b * NKV + kv) * HD + d) * S_ + s0 + s8) = o;
    }
  }
}

// ---------------- 4-phase 256x192 GEMM (QKV): 256 blocks = 1/CU ---------------- (r11)
template <typename OutT>
__global__ __launch_bounds__(512) void gemm192(const ushort* __restrict__ A,
                                               const ushort* __restrict__ Bm,
                                               OutT* __restrict__ C,
                                               int M, int N, int K) {
  __shared__ __align__(16) ushort SM[57344];   // 112KB
  int nb = N / 192;
  int bx = blockIdx.x % nb, by = blockIdx.x / nb;
  int m0 = by << 8;
  int n0 = bx * 192;
  int tid = threadIdx.x;
  int lane = tid & 63, w = tid >> 6;
  int l15 = lane & 15, lg = lane >> 4;
  int wm = (w >> 2) * 128;
  int wn = (w & 3) * 48;
  int pA = w >> 2;

  int srow = tid >> 3;
  int cb   = ((tid & 7) * 16) ^ ((srow & 7) << 4);
  const ushort* sA = A  + (size_t)(m0 + srow) * K + (cb >> 1);
  const ushort* sB = Bm + (size_t)(n0 + srow) * K + (cb >> 1);
  size_t rstep = (size_t)64 * K;
  int nkt = K >> 6;

  auto STG_A = [&](int t, int db) {
    ushort* base = SM + db * 28672 + (w << 9);
    const ushort* a0 = sA + (size_t)t * 64;
    async16(a0,             base);
    async16(a0 + rstep,     base + 4096);
    async16(a0 + 2 * rstep, base + 8192);
    async16(a0 + 3 * rstep, base + 12288);
  };
  auto STG_B = [&](int t, int db) {
    ushort* base = SM + db * 28672 + 16384 + (w << 9);
    const ushort* b0 = sB + (size_t)t * 64;
    async16(b0,             base);
    async16(b0 + rstep,     base + 4096);
    async16(b0 + 2 * rstep, base + 8192);
  };

  fv4 acc[8][3] = {};
  sv8 alo[4][2], ahi[4][2], b01[2][2], b2v[2];

  STG_A(0, 0); STG_B(0, 0);
  { int t1 = nkt > 1 ? 1 : 0; STG_A(t1, 1); STG_B(t1, 1); }
  asm volatile("s_waitcnt vmcnt(7)");
  __builtin_amdgcn_s_barrier();

  for (int t = 0; t < nkt; ++t) {
    int db = t & 1;
    int t2 = t + 2 < nkt ? t + 2 : nkt - 1;
    const char* Ab = (const char*)(SM + db * 28672) + pA * 16384;
    const char* Bb = (const char*)(SM + db * 28672) + 32768;

    // ---- P1: read A-lo(8) + B j0,j1(4); MFMA A-lo x {j0,j1} ----
#pragma unroll
    for (int m = 0; m < 4; ++m)
#pragma unroll
      for (int kk = 0; kk < 2; ++kk) {
        int row = m * 16 + l15;
        alo[m][kk] = *(const sv8*)(Ab + row * 128 + ((kk * 64 + lg * 16) ^ ((row & 7) << 4)));
      }
#pragma unroll
    for (int j = 0; j < 2; ++j)
#pragma unroll
      for (int kk = 0; kk < 2; ++kk) {
        int row = wn + j * 16 + l15;
        b01[j][kk] = *(const sv8*)(Bb + row * 128 + ((kk * 64 + lg * 16) ^ ((row & 7) << 4)));
      }
    __builtin_amdgcn_s_barrier();
    asm volatile("s_waitcnt lgkmcnt(0)");
    __builtin_amdgcn_s_setprio(1);
#pragma unroll
    for (int m = 0; m < 4; ++m)
#pragma unroll
      for (int j = 0; j < 2; ++j)
#pragma unroll
        for (int kk = 0; kk < 2; ++kk)
          acc[m][j] = __builtin_amdgcn_mfma_f32_16x16x32_bf16(alo[m][kk], b01[j][kk], acc[m][j], 0, 0, 0);
    __builtin_amdgcn_s_setprio(0);
    __builtin_amdgcn_s_barrier();

    // ---- P2: read A-hi(8) + B j2(2); MFMA A-lo x j2 ----
#pragma unroll
    for (int m = 0; m < 4; ++m)
#pragma unroll
      for (int kk = 0; kk < 2; ++kk) {
        int row = 64 + m * 16 + l15;
        ahi[m][kk] = *(const sv8*)(Ab + row * 128 + ((kk * 64 + lg * 16) ^ ((row & 7) << 4)));
      }
#pragma unroll
    for (int kk = 0; kk < 2; ++kk) {
      int row = wn + 32 + l15;
      b2v[kk] = *(const sv8*)(Bb + row * 128 + ((kk * 64 + lg * 16) ^ ((row & 7) << 4)));
    }
    __builtin_amdgcn_s_barrier();
    asm volatile("s_waitcnt lgkmcnt(0)");
    __builtin_amdgcn_s_setprio(1);
#pragma unroll
    for (int m = 0; m < 4; ++m)
#pragma unroll
      for (int kk = 0; kk < 2; ++kk)
        acc[m][2] = __builtin_amdgcn_mfma_f32_16x16x32_bf16(alo[m][kk], b2v[kk], acc[m][2], 0, 0, 0);
    __builtin_amdgcn_s_setprio(0);
    __builtin_amdgcn_s_barrier();

    // ---- P3: stage A(T+2); MFMA A-hi x {j0,j1} ----
    STG_A(t2, db);
    __builtin_amdgcn_s_barrier();
    __builtin_amdgcn_s_setprio(1);
#pragma unroll
    for (int m = 0; m < 4; ++m)
#pragma unroll
      for (int j = 0; j < 2; ++j)
#pragma unroll
        for (int kk = 0; kk < 2; ++kk)
          acc[m + 4][j] = __builtin_amdgcn_mfma_f32_16x16x32_bf16(ahi[m][kk], b01[j][kk], acc[m + 4][j], 0, 0, 0);
    __builtin_amdgcn_s_setprio(0);
    __builtin_amdgcn_s_barrier();

    // ---- P4: stage B(T+2); vmcnt(7) -> T+1 landed; MFMA A-hi x j2 ----
    STG_B(t2, db);
    asm volatile("s_waitcnt vmcnt(7)");
    __builtin_amdgcn_s_barrier();
    __builtin_amdgcn_s_setprio(1);
#pragma unroll
    for (int m = 0; m < 4; ++m)
#pragma unroll
      for (int kk = 0; kk < 2; ++kk)
        acc[m + 4][2] = __builtin_amdgcn_mfma_f32_16x16x32_bf16(ahi[m][kk], b2v[kk], acc[m + 4][2], 0, 0, 0);
    __builtin_amdgcn_s_setprio(0);
    __builtin_amdgcn_s_barrier();
  }

  asm volatile("s_waitcnt vmcnt(0)");
#pragma unroll
  for (int m = 0; m < 8; ++m)
#pragma unroll
    for (int j = 0; j < 3; ++j)
#pragma unroll
      for (int r = 0; r < 4; ++r) {
        int row = m0 + wm + m * 16 + lg * 4 + r;
        int col = n0 + wn + j * 16 + l15;
        if constexpr (sizeof(OutT) == 2) C[(size_t)row * N + col] = (OutT)f2bf(acc[m][j][r]);
        else                             C[(size_t)row * N + col] = (OutT)acc[m][j][r];
      }
}

// ---------------- 2-phase 256x128 GEMM (o-proj): 16 MFMA per phase --------------- (r11)
template <typename OutT>
__global__ __launch_bounds__(512) void gemmOP(const ushort* __restrict__ A,
                                              const ushort* __restrict__ Bm,
                                              OutT* __restrict__ C,
                                              int M, int N, int K) {
  __shared__ __align__(16) ushort SM[49152];   // 96KB
  int nb = N >> 7;
  int bx = blockIdx.x % nb, by = blockIdx.x / nb;
  int m0 = by << 8, n0 = bx << 7;
  int tid = threadIdx.x;
  int lane = tid & 63, w = tid >> 6;
  int l15 = lane & 15, lg = lane >> 4;
  int wm = (w >> 2) * 128;
  int wn = (w & 3) * 32;
  int pA = (w >> 2);

  int srow = tid >> 3;
  int cb   = ((tid & 7) * 16) ^ ((srow & 7) << 4);
  const ushort* sA0 = A  + (size_t)(m0 + srow) * K + (cb >> 1);
  const ushort* sB0 = Bm + (size_t)(n0 + srow) * K + (cb >> 1);
  const ushort* srcs[3] = { sA0, sA0 + (size_t)128 * K, sB0 };
  size_t rstep = (size_t)64 * K;

  int nkt = K >> 6;

  auto STG = [&](int part, int t, int db) {
    ushort* d0 = SM + db * 24576 + part * 8192 + (w << 9);
    const ushort* s0 = srcs[part] + t * 64;
    async16(s0, d0);
    async16(s0 + rstep, d0 + 4096);
  };

  fv4 acc[8][2] = {};
  sv8 a[8][2], b[2][2];

#pragma unroll
  for (int p = 0; p < 3; ++p) STG(p, 0, 0);
  {
    int t1 = 1 < nkt ? 1 : 0;
#pragma unroll
    for (int p = 0; p < 3; ++p) STG(p, t1, 1);
  }
  asm volatile("s_waitcnt vmcnt(6)");
  __builtin_amdgcn_s_barrier();

  for (int t = 0; t < nkt; ++t) {
    int db = t & 1;
    int t2 = t + 2 < nkt ? t + 2 : nkt - 1;
    const char* Ab = (const char*)SM + db * 49152 + pA * 16384;
    const char* Bb = (const char*)SM + db * 49152 + 32768;

    // ---- P1: read all A (16) + B j0,j1 (4); MFMA A-lo x {j0,j1} ----
#pragma unroll
    for (int m = 0; m < 8; ++m)
#pragma unroll
      for (int kk = 0; kk < 2; ++kk) {
        int row = m * 16 + l15;
        a[m][kk] = *(const sv8*)(Ab + row * 128 + ((kk * 64 + lg * 16) ^ ((row & 7) << 4)));
      }
#pragma unroll
    for (int j = 0; j < 2; ++j)
#pragma unroll
      for (int kk = 0; kk < 2; ++kk) {
        int row = wn + j * 16 + l15;
        b[j][kk] = *(const sv8*)(Bb + row * 128 + ((kk * 64 + lg * 16) ^ ((row & 7) << 4)));
      }
    __builtin_amdgcn_s_barrier();
    asm volatile("s_waitcnt lgkmcnt(0)");
    __builtin_amdgcn_s_setprio(1);
#pragma unroll
    for (int m = 0; m < 4; ++m)
#pragma unroll
      for (int j = 0; j < 2; ++j)
#pragma unroll
        for (int kk = 0; kk < 2; ++kk)
          acc[m][j] = __builtin_amdgcn_mfma_f32_16x16x32_bf16(a[m][kk], b[j][kk], acc[m][j], 0, 0, 0);
    __builtin_amdgcn_s_setprio(0);
    __builtin_amdgcn_s_barrier();

    // ---- P2: stage T+2 (6 loads); vmcnt(6) -> T+1 landed; MFMA A-hi x {j0,j1} ----
    STG(0, t2, db);
    STG(1, t2, db);
    STG(2, t2, db);
    asm volatile("s_waitcnt vmcnt(6)");
    __builtin_amdgcn_s_barrier();
    __builtin_amdgcn_s_setprio(1);
#pragma unroll
    for (int m = 0; m < 4; ++m)
#pragma unroll
      for (int j = 0; j < 2; ++j)
#pragma unroll
        for (int kk = 0; kk < 2; ++kk)
          acc[m + 4][j] = __builtin_amdgcn_mfma_f32_16x16x32_bf16(a[m + 4][kk], b[j][kk], acc[m + 4][j], 0, 0, 0);
    __builtin_amdgcn_s_setprio(0);
    __builtin_amdgcn_s_barrier();
  }

  asm volatile("s_waitcnt vmcnt(0)");
#pragma unroll
  for (int m = 0; m < 8; ++m)
#pragma unroll
    for (int j = 0; j < 2; ++j)
#pragma unroll
      for (int r = 0; r < 4; ++r) {
        int row = m0 + wm + m * 16 + lg * 4 + r;
        int col = n0 + wn + j * 16 + l15;
        if constexpr (sizeof(OutT) == 2) C[(size_t)row * N + col] = (OutT)f2bf(acc[m][j][r]);
        else                             C[(size_t)row * N + col] = (OutT)acc[m][j][r];
      }
}

// ---------------- Flash attention (causal, GQA) ---------------- (r11 verbatim)
// 512 thr = 8 waves; two 4-wave halves k-split one q-tile; dbuf K/V in LDS;
// K 16-slot swizzle, V 64x256B layout; in-LDS f32 merge; 2 passes (pr, 15-pr).
__global__ __launch_bounds__(512, 2) void attn_kernel(const ushort* __restrict__ Q,
                                                      const ushort* __restrict__ Kr,
                                                      const ushort* __restrict__ Vt,
                                                      ushort* __restrict__ O) {
  __shared__ __align__(16) ushort SMEM[65536];   // 128KB

  int blk = blockIdx.x;
  int bh  = blk & 31;
  int pr  = blk >> 5;
  int h   = bh & 15;
  int b   = bh >> 4;
  int kv  = h >> 2;
  int lane = threadIdx.x & 63, w = threadIdx.x >> 6;
  int wg = w & 3, Hf = w >> 2;
  int l31 = lane & 31, hh = lane >> 5;

  const ushort* Qbase = Q  + (size_t)(b * NH  + h ) * S_ * HD;
  const ushort* Kbase = Kr + (size_t)(b * NKV + kv) * S_ * HD;
  const ushort* Vbase = Vt + (size_t)(b * NKV + kv) * HD * S_;

  const ushort* kSrc[4]; ushort* kDst[2][4];
  const ushort* vSrc[4]; ushort* vDst[2][4];
#pragma unroll
  for (int it = 0; it < 4; ++it) {
    int lin = it * 4096 + wg * 1024 + lane * 16;
    { int row = lin >> 8; int cbv = (lin & 255) ^ ((row & 15) << 4);
      kSrc[it] = Kbase + (size_t)row * HD + (cbv >> 1); }
    { int row = lin >> 8; int cp = lin & 255; int cl = cp ^ ((row & 15) << 4);
      int d = row + ((cl >> 7) << 6);       // half-bit -> +64 d
      int koff = (cl & 127) >> 1;
      vSrc[it] = Vbase + (size_t)d * S_ + koff; }
#pragma unroll
    for (int buf = 0; buf < 2; ++buf) {
      kDst[buf][it] = SMEM + Hf * 16384 + buf * 8192 + ((it * 4096 + wg * 1024) >> 1);
      vDst[buf][it] = SMEM + 32768 + Hf * 16384 + buf * 8192 + ((it * 4096 + wg * 1024) >> 1);
    }
  }

  float* cML = (float*)SMEM;
  float* cO  = (float*)SMEM + 512;

  for (int pass = 0; pass < 2; ++pass) {
    int qt = pass ? (15 - pr) : pr;
    int q0 = qt << 7;
    int qrow_w = q0 + wg * 32;
    int myq    = qrow_w + l31;
    int nj     = qt + 1;
    int ktbase = Hf * nj;

    sv8 qf[8];
#pragma unroll
    for (int kk = 0; kk < 8; ++kk)
      qf[kk] = *(const sv8*)(Qbase + (size_t)myq * HD + kk * 16 + hh * 8);

    fv16 oacc[4] = {};
    float mrun = -1e30f, lrun = 0.f;

    {
      size_t k0 = (size_t)ktbase << 6;
#pragma unroll
      for (int it = 0; it < 4; ++it) async16(kSrc[it] + k0 * HD, kDst[0][it]);
#pragma unroll
      for (int it = 0; it < 4; ++it) async16(vSrc[it] + k0,      vDst[0][it]);
    }

    for (int j = 0; j < nj; ++j) {
      int cur = j & 1, nxt = cur ^ 1;
      __syncthreads();
      if (j + 1 < nj) {
        size_t k0n = (size_t)(ktbase + j + 1) << 6;
#pragma unroll
        for (int it = 0; it < 4; ++it) async16(kSrc[it] + k0n * HD, kDst[nxt][it]);
#pragma unroll
        for (int it = 0; it < 4; ++it) async16(vSrc[it] + k0n,      vDst[nxt][it]);
      }
      const char* KsC = (const char*)(SMEM + Hf * 16384 + cur * 8192);
      const char* VsC = (const char*)(SMEM + 32768 + Hf * 16384 + cur * 8192);
      int k0 = (ktbase + j) << 6;

      fv16 sacc[2] = {};
      __builtin_amdgcn_s_setprio(1);
#pragma unroll
      for (int kk = 0; kk < 8; ++kk) {
        int cbq = kk * 32 + hh * 16;
        int r0 = l31, r1 = 32 + l31;
        sv8 kf0 = *(const sv8*)(KsC + r0 * 256 + (cbq ^ ((r0 & 15) << 4)));
        sv8 kf1 = *(const sv8*)(KsC + r1 * 256 + (cbq ^ ((r1 & 15) << 4)));
        sacc[0] = __builtin_amdgcn_mfma_f32_32x32x16_bf16(kf0, qf[kk], sacc[0], 0, 0, 0);
        sacc[1] = __builtin_amdgcn_mfma_f32_32x32x16_bf16(kf1, qf[kk], sacc[1], 0, 0, 0);
      }
      __builtin_amdgcn_s_setprio(0);

      if (k0 + 63 > qrow_w) {
        int thr = myq - k0 - 4 * hh;
#pragma unroll
        for (int t = 0; t < 2; ++t)
#pragma unroll
          for (int r = 0; r < 16; ++r) {
            int kp = t * 32 + (r & 3) + 8 * (r >> 2);
            if (kp > thr) sacc[t][r] = -1e38f;
          }
      }

      float tmax = fmaxf(tmax16(sacc[0]), tmax16(sacc[1]));
      tmax = fmaxf(tmax, __shfl_xor(tmax, 32, 64));

      if (__any(tmax > mrun + 8.0f)) {
        float mnew = fmaxf(mrun, tmax);
        float esc  = fast_exp2(mrun - mnew);
        lrun *= esc;
        float er[16];
#pragma unroll
        for (int r = 0; r < 16; ++r) er[r] = __shfl(esc, (r & 3) + 8 * (r >> 2) + 4 * hh, 64);
#pragma unroll
        for (int d0 = 0; d0 < 4; ++d0)
#pragma unroll
          for (int r = 0; r < 16; ++r) oacc[d0][r] *= er[r];
        mrun = mnew;
      }

#pragma unroll
      for (int t = 0; t < 2; ++t)
#pragma unroll
        for (int r = 0; r < 16; ++r) sacc[t][r] = fast_exp2(sacc[t][r] - mrun);
      float psum = tsum16(sacc[0]) + tsum16(sacc[1]);
      psum += __shfl_xor(psum, 32, 64);
      lrun += psum;

      union Frag { unsigned int u[4]; sv8 v; } pa[4];
#pragma unroll
      for (int t = 0; t < 2; ++t)
#pragma unroll
        for (int half = 0; half < 2; ++half) {
          int cbq = half * 8;
          unsigned int a0 = cvtpk(sacc[t][cbq + 0], sacc[t][cbq + 1]);
          unsigned int a1 = cvtpk(sacc[t][cbq + 2], sacc[t][cbq + 3]);
          unsigned int b0 = cvtpk(sacc[t][cbq + 4], sacc[t][cbq + 5]);
          unsigned int b1 = cvtpk(sacc[t][cbq + 6], sacc[t][cbq + 7]);
          unsigned int a0p = xhalf(a0), a1p = xhalf(a1);
          unsigned int b0p = xhalf(b0), b1p = xhalf(b1);
          pa[2 * t + half].u[0] = hh ? b0p : a0;
          pa[2 * t + half].u[1] = hh ? b1p : a1;
          pa[2 * t + half].u[2] = hh ? b0  : a0p;
          pa[2 * t + half].u[3] = hh ? b1  : a1p;
        }

      __builtin_amdgcn_s_setprio(1);
#pragma unroll
      for (int ks = 0; ks < 4; ++ks) {
#pragma unroll
        for (int d0 = 0; d0 < 4; ++d0) {
          int d = d0 * 32 + l31;
          int row = d & 63;
          int cl = ((d >> 6) << 7) + ks * 32 + hh * 16;
          sv8 vf = *(const sv8*)(VsC + row * 256 + (cl ^ ((row & 15) << 4)));
          oacc[d0] = __builtin_amdgcn_mfma_f32_32x32x16_bf16(pa[ks].v, vf, oacc[d0], 0, 0, 0);
        }
      }
      __builtin_amdgcn_s_setprio(0);
    }

    __syncthreads();
    if (Hf) {
      int base = wg * 64 + lane;
      cML[base * 2]     = mrun;
      cML[base * 2 + 1] = lrun;
      float* dst = cO + base * 65;
#pragma unroll
      for (int d0 = 0; d0 < 4; ++d0)
#pragma unroll
        for (int r = 0; r < 16; ++r) dst[d0 * 16 + r] = oacc[d0][r];
    }
    __syncthreads();
    if (!Hf) {
      int base = wg * 64 + lane;
      float m2 = cML[base * 2], l2 = cML[base * 2 + 1];
      const float* src = cO + base * 65;
      float m  = fmaxf(mrun, m2);
      float e1 = fast_exp2(mrun - m), e2 = fast_exp2(m2 - m);
      float l  = lrun * e1 + l2 * e2;
      float inv = 1.0f / l;
      float f1 = e1 * inv, f2 = e2 * inv;
      float f1b[16], f2b[16];
#pragma unroll
      for (int r = 0; r < 16; ++r) {
        int ro = (r & 3) + 8 * (r >> 2) + 4 * hh;
        f1b[r] = __shfl(f1, ro, 64);
        f2b[r] = __shfl(f2, ro, 64);
      }
#pragma unroll
      for (int r = 0; r < 16; ++r) {
        int q = qrow_w + (r & 3) + 8 * (r >> 2) + 4 * hh;
#pragma unroll
        for (int d0 = 0; d0 < 4; ++d0) {
          int d = d0 * 32 + l31;
          float val = oacc[d0][r] * f1b[r] + src[d0 * 16 + r] * f2b[r];
          O[(size_t)(b * S_ + q) * DIM_ + h * HD + d] = f2bf(val);
        }
      }
    }
    __syncthreads();
  }
}

// ---------------- host launcher ----------------
extern "C" void kernel_launch(void* const* d_in, const int* in_sizes, int n_in,
                              void* d_out, int out_size, void* d_ws, size_t ws_size,
                              hipStream_t stream) {
  const float* x  = (const float*)d_in[0];
  const float* wq = (const float*)d_in[1];
  const float* wk = (const float*)d_in[2];
  const float* wv = (const float*)d_in[3];
  const float* wo = (const float*)d_in[4];
  const float* fc = (const float*)d_in[5];
  const float* fs = (const float*)d_in[6];
  float* out = (float*)d_out;

  char* ws = (char*)d_ws;
  size_t off = 0;
  auto alloc = [&](size_t bytes) -> ushort* {
    ushort* p = (ushort*)(ws + off);
    off += (bytes + 255) & ~(size_t)255;
    return p;
  };
  ushort* xb    = alloc((size_t)B_ * S_ * DIM_ * 2);        // 16.8MB
  ushort* wqkvb = alloc((size_t)QKVN * DIM_ * 2);           // 12.6MB
  ushort* wob   = alloc((size_t)DIM_ * DIM_ * 2);           // 8MB
  ushort* qkvr  = alloc((size_t)B_ * S_ * QKVN * 2);        // 25.2MB
  ushort* qr    = alloc((size_t)B_ * S_ * DIM_ * 2);        // 16MB
  ushort* kr    = alloc((size_t)B_ * S_ * NKV * HD * 2);    // 4MB
  ushort* vtb   = alloc((size_t)B_ * S_ * NKV * HD * 2);    // 4MB
  ushort* obf   = alloc((size_t)B_ * S_ * DIM_ * 2);        // 16MB
  (void)ws_size; (void)n_in; (void)in_sizes; (void)out_size;

  // all f32->bf16 converts in ONE launch (x + wq|wk|wv + wo)
  const int cvt_elems = 2 * DIM_ * DIM_ /*x*/ + 2 * DIM_ * DIM_ /*wq+wo*/
                      + 2 * NKV * HD * DIM_ /*wk+wv*/;
  cvtall_kernel<<<cvt_elems / 1024, 256, 0, stream>>>(x, wq, wk, wv, wo, xb, wqkvb, wob);

  // fused QKV projection: [4096, 2048] x [3072, 2048]^T -> [4096, 3072] (4-phase 256x192)
  gemm192<ushort><<<(B_ * S_ / 256) * (QKVN / 192), 512, 0, stream>>>(xb, wqkvb, qkvr,
                                                                     B_ * S_, QKVN, DIM_);

  // fused prep: rope Q+K + V transpose in ONE launch
  const float qscale = 0.08838834764831845f * 1.4426950408889634f;
  prep_kernel<<<5120 + B_ * NKV * (S_ / 128), 256, 0, stream>>>(qkvr, fc, fs, qr, kr, vtb, qscale);

  // attention: 256 blocks x 512 thr; uniform 17-tile chains per wave (k-split + pair)
  attn_kernel<<<B_ * NH * 8, 512, 0, stream>>>(qr, kr, vtb, obf);

  // output projection -> f32 d_out (2-phase 256x128 tiles, 256 blocks = 1/CU)
  gemmOP<float><<<(B_ * S_ / 256) * (DIM_ / 128), 512, 0, stream>>>(obf, wob, out, B_ * S_, DIM_, DIM_);
}

// Round 16
// 180.700 us; speedup vs baseline: 1.9945x; 1.0517x over previous
//
#include <hip/hip_runtime.h>
#include <hip/hip_bf16.h>

// Problem constants
#define B_   2
#define S_   2048
#define DIM_ 2048
#define NH   16
#define NKV  4
#define HD   128
#define QKVN 3072   // fused projection width: 2048 (Q) + 512 (K) + 512 (V)

typedef __attribute__((ext_vector_type(8)))  short  sv8;   // 8 x bf16 (MFMA operand)
typedef __attribute__((ext_vector_type(8)))  ushort usv8;
typedef __attribute__((ext_vector_type(4)))  float  fv4;
typedef __attribute__((ext_vector_type(16))) float  fv16;

__device__ __forceinline__ float fast_exp2(float x) {
  return __builtin_amdgcn_exp2f(x);   // v_exp_f32 (base-2)
}

__device__ __forceinline__ ushort f2bf(float f) {
  __hip_bfloat16 h = __float2bfloat16(f);
  union { __hip_bfloat16 h; ushort u; } c; c.h = h; return c.u;
}
__device__ __forceinline__ float bf2f(ushort u) {
  union { unsigned int i; float f; } c; c.i = ((unsigned)u) << 16; return c.f;
}

// pack two f32 -> two bf16 in one u32 (possibly RTZ — only for MFMA operands)
__device__ __forceinline__ unsigned int cvtpk(float lo, float hi) {
  unsigned int r;
  asm("v_cvt_pk_bf16_f32 %0, %1, %2" : "=v"(r) : "v"(lo), "v"(hi));
  return r;
}
// exchange with partner lane (lane ^ 32)
__device__ __forceinline__ unsigned int xhalf(unsigned int x) {
  return (unsigned int)__shfl_xor((int)x, 32, 64);
}

// tree reductions over a 16-vector (depth 5, ILP-friendly)
__device__ __forceinline__ float tmax16(const fv16& v) {
  float a = fmaxf(fmaxf(v[0], v[1]),  fmaxf(v[2], v[3]));
  float b = fmaxf(fmaxf(v[4], v[5]),  fmaxf(v[6], v[7]));
  float c = fmaxf(fmaxf(v[8], v[9]),  fmaxf(v[10], v[11]));
  float d = fmaxf(fmaxf(v[12], v[13]), fmaxf(v[14], v[15]));
  return fmaxf(fmaxf(a, b), fmaxf(c, d));
}
__device__ __forceinline__ float tsum16(const fv16& v) {
  float a = (v[0] + v[1]) + (v[2] + v[3]);
  float b = (v[4] + v[5]) + (v[6] + v[7]);
  float c = (v[8] + v[9]) + (v[10] + v[11]);
  float d = (v[12] + v[13]) + (v[14] + v[15]);
  return (a + b) + (c + d);
}

// async global->LDS, 16B per lane; LDS dest is wave-uniform base (HW adds lane*16).
__device__ __forceinline__ void async16(const void* g, void* l) {
  __builtin_amdgcn_global_load_lds(
      (const __attribute__((address_space(1))) unsigned int*)g,
      (__attribute__((address_space(3))) unsigned int*)l, 16, 0, 0);
}

// ---------------- fused f32->bf16 convert: x, then wq|wk|wv -> wqkvb, wo -> wob ----
__global__ void cvtall_kernel(const float* __restrict__ x,
                              const float* __restrict__ wq, const float* __restrict__ wk,
                              const float* __restrict__ wv, const float* __restrict__ wo,
                              ushort* __restrict__ xb,
                              ushort* __restrict__ wqkvb, ushort* __restrict__ wob) {
  const int NX = 2 * 2048 * 2048;                 // x elems
  const int NQ = 2048 * 2048, NK = 512 * 2048;    // weight ranges (1024-aligned)
  int i = (blockIdx.x * 256 + threadIdx.x) * 4;
  const float* src; ushort* dst;
  if (i < NX) { src = x + i; dst = xb + i; }
  else {
    int j = i - NX;
    if (j < NQ)               { src = wq + j;             dst = wqkvb + j; }
    else if (j < NQ + NK)     { src = wk + (j - NQ);      dst = wqkvb + j; }
    else if (j < NQ + 2 * NK) { src = wv + (j - NQ - NK); dst = wqkvb + j; }
    else                      { int k = j - (NQ + 2 * NK); src = wo + k; dst = wob + k; }
  }
  fv4 v = *(const fv4*)src;
  ushort4 o;
  o.x = f2bf(v[0]); o.y = f2bf(v[1]); o.z = f2bf(v[2]); o.w = f2bf(v[3]);
  *(ushort4*)dst = o;
}

// ---------------- fused RoPE Q+K, relayout to (B, heads, S, HD) ---------------- (no LDS)
__global__ void rope2_kernel(const ushort* __restrict__ qkv, const float* __restrict__ fc,
                             const float* __restrict__ fs, ushort* __restrict__ qr,
                             ushort* __restrict__ kr, float qscale) {
  int t = blockIdx.x * 256 + threadIdx.x;   // B*S*20*16 threads, 8 elems each
  int grp = t & 15;
  int u   = t >> 4;
  int h2  = u % 20;
  int s   = (u / 20) % S_;
  int b   = u / (20 * S_);
  bool isQ  = h2 < 16;
  int h     = isQ ? h2 : h2 - 16;
  int heads = isQ ? NH : NKV;
  float scale = isQ ? qscale : 1.0f;
  const ushort* src = qkv + (size_t)(b * S_ + s) * QKVN + (isQ ? 0 : 2048) + h * HD + grp * 8;
  sv8 v = *(const sv8*)src;
  fv4 c  = *(const fv4*)(fc + s * 64 + grp * 4);
  fv4 sn = *(const fv4*)(fs + s * 64 + grp * 4);
  sv8 o;
#pragma unroll
  for (int p = 0; p < 4; ++p) {
    float re = bf2f((ushort)v[2 * p]);
    float im = bf2f((ushort)v[2 * p + 1]);
    float orr = (re * c[p] - im * sn[p]) * scale;
    float oi  = (re * sn[p] + im * c[p]) * scale;
    o[2 * p]     = (short)f2bf(orr);
    o[2 * p + 1] = (short)f2bf(oi);
  }
  ushort* dst = (isQ ? qr : kr) + ((size_t)(b * heads + h) * S_ + s) * HD + grp * 8;
  *(sv8*)dst = o;
}

// ---------------- V transpose: rows of fused qkv -> (B,KVH,HD,S) ----------------
__global__ __launch_bounds__(256) void vtrans_kernel(const ushort* __restrict__ vraw,
                                                     ushort* __restrict__ vt, int rowstride) {
  __shared__ ushort tile[128][136];
  int blk = blockIdx.x;            // (b*NKV+kv)*16 + st
  int st  = blk & 15;
  int kvb = blk >> 4;
  int kv  = kvb & 3;
  int b   = kvb >> 2;
  int s0  = st << 7;
#pragma unroll
  for (int it = 0; it < 8; ++it) {
    int t = it * 256 + threadIdx.x;
    int srow = t >> 4;
    int d8 = (t & 15) * 8;
    usv8 v = *(const usv8*)(vraw + (size_t)(b * S_ + s0 + srow) * rowstride + kv * HD + d8);
#pragma unroll
    for (int j = 0; j < 8; ++j) tile[d8 + j][srow] = v[j];
  }
  __syncthreads();
#pragma unroll
  for (int it = 0; it < 8; ++it) {
    int t = it * 256 + threadIdx.x;
    int d = t >> 4;
    int s8 = (t & 15) * 8;
    usv8 o;
#pragma unroll
    for (int j = 0; j < 8; ++j) o[j] = tile[d][s8 + j];
    *(usv8*)(vt + ((size_t)(b * NKV + kv) * HD + d) * S_ + s0 + s8) = o;
  }
}

// ---------------- 4-phase 256x192 GEMM (QKV): 256 blocks = 1/CU ---------------- (r11)
template <typename OutT>
__global__ __launch_bounds__(512) void gemm192(const ushort* __restrict__ A,
                                               const ushort* __restrict__ Bm,
                                               OutT* __restrict__ C,
                                               int M, int N, int K) {
  __shared__ __align__(16) ushort SM[57344];   // 112KB
  int nb = N / 192;
  int bx = blockIdx.x % nb, by = blockIdx.x / nb;
  int m0 = by << 8;
  int n0 = bx * 192;
  int tid = threadIdx.x;
  int lane = tid & 63, w = tid >> 6;
  int l15 = lane & 15, lg = lane >> 4;
  int wm = (w >> 2) * 128;
  int wn = (w & 3) * 48;
  int pA = w >> 2;

  int srow = tid >> 3;
  int cb   = ((tid & 7) * 16) ^ ((srow & 7) << 4);
  const ushort* sA = A  + (size_t)(m0 + srow) * K + (cb >> 1);
  const ushort* sB = Bm + (size_t)(n0 + srow) * K + (cb >> 1);
  size_t rstep = (size_t)64 * K;
  int nkt = K >> 6;

  auto STG_A = [&](int t, int db) {
    ushort* base = SM + db * 28672 + (w << 9);
    const ushort* a0 = sA + (size_t)t * 64;
    async16(a0,             base);
    async16(a0 + rstep,     base + 4096);
    async16(a0 + 2 * rstep, base + 8192);
    async16(a0 + 3 * rstep, base + 12288);
  };
  auto STG_B = [&](int t, int db) {
    ushort* base = SM + db * 28672 + 16384 + (w << 9);
    const ushort* b0 = sB + (size_t)t * 64;
    async16(b0,             base);
    async16(b0 + rstep,     base + 4096);
    async16(b0 + 2 * rstep, base + 8192);
  };

  fv4 acc[8][3] = {};
  sv8 alo[4][2], ahi[4][2], b01[2][2], b2v[2];

  STG_A(0, 0); STG_B(0, 0);
  { int t1 = nkt > 1 ? 1 : 0; STG_A(t1, 1); STG_B(t1, 1); }
  asm volatile("s_waitcnt vmcnt(7)");
  __builtin_amdgcn_s_barrier();

  for (int t = 0; t < nkt; ++t) {
    int db = t & 1;
    int t2 = t + 2 < nkt ? t + 2 : nkt - 1;
    const char* Ab = (const char*)(SM + db * 28672) + pA * 16384;
    const char* Bb = (const char*)(SM + db * 28672) + 32768;

    // ---- P1: read A-lo(8) + B j0,j1(4); MFMA A-lo x {j0,j1} ----
#pragma unroll
    for (int m = 0; m < 4; ++m)
#pragma unroll
      for (int kk = 0; kk < 2; ++kk) {
        int row = m * 16 + l15;
        alo[m][kk] = *(const sv8*)(Ab + row * 128 + ((kk * 64 + lg * 16) ^ ((row & 7) << 4)));
      }
#pragma unroll
    for (int j = 0; j < 2; ++j)
#pragma unroll
      for (int kk = 0; kk < 2; ++kk) {
        int row = wn + j * 16 + l15;
        b01[j][kk] = *(const sv8*)(Bb + row * 128 + ((kk * 64 + lg * 16) ^ ((row & 7) << 4)));
      }
    __builtin_amdgcn_s_barrier();
    asm volatile("s_waitcnt lgkmcnt(0)");
    __builtin_amdgcn_s_setprio(1);
#pragma unroll
    for (int m = 0; m < 4; ++m)
#pragma unroll
      for (int j = 0; j < 2; ++j)
#pragma unroll
        for (int kk = 0; kk < 2; ++kk)
          acc[m][j] = __builtin_amdgcn_mfma_f32_16x16x32_bf16(alo[m][kk], b01[j][kk], acc[m][j], 0, 0, 0);
    __builtin_amdgcn_s_setprio(0);
    __builtin_amdgcn_s_barrier();

    // ---- P2: read A-hi(8) + B j2(2); MFMA A-lo x j2 ----
#pragma unroll
    for (int m = 0; m < 4; ++m)
#pragma unroll
      for (int kk = 0; kk < 2; ++kk) {
        int row = 64 + m * 16 + l15;
        ahi[m][kk] = *(const sv8*)(Ab + row * 128 + ((kk * 64 + lg * 16) ^ ((row & 7) << 4)));
      }
#pragma unroll
    for (int kk = 0; kk < 2; ++kk) {
      int row = wn + 32 + l15;
      b2v[kk] = *(const sv8*)(Bb + row * 128 + ((kk * 64 + lg * 16) ^ ((row & 7) << 4)));
    }
    __builtin_amdgcn_s_barrier();
    asm volatile("s_waitcnt lgkmcnt(0)");
    __builtin_amdgcn_s_setprio(1);
#pragma unroll
    for (int m = 0; m < 4; ++m)
#pragma unroll
      for (int kk = 0; kk < 2; ++kk)
        acc[m][2] = __builtin_amdgcn_mfma_f32_16x16x32_bf16(alo[m][kk], b2v[kk], acc[m][2], 0, 0, 0);
    __builtin_amdgcn_s_setprio(0);
    __builtin_amdgcn_s_barrier();

    // ---- P3: stage A(T+2); MFMA A-hi x {j0,j1} ----
    STG_A(t2, db);
    __builtin_amdgcn_s_barrier();
    __builtin_amdgcn_s_setprio(1);
#pragma unroll
    for (int m = 0; m < 4; ++m)
#pragma unroll
      for (int j = 0; j < 2; ++j)
#pragma unroll
        for (int kk = 0; kk < 2; ++kk)
          acc[m + 4][j] = __builtin_amdgcn_mfma_f32_16x16x32_bf16(ahi[m][kk], b01[j][kk], acc[m + 4][j], 0, 0, 0);
    __builtin_amdgcn_s_setprio(0);
    __builtin_amdgcn_s_barrier();

    // ---- P4: stage B(T+2); vmcnt(7) -> T+1 landed; MFMA A-hi x j2 ----
    STG_B(t2, db);
    asm volatile("s_waitcnt vmcnt(7)");
    __builtin_amdgcn_s_barrier();
    __builtin_amdgcn_s_setprio(1);
#pragma unroll
    for (int m = 0; m < 4; ++m)
#pragma unroll
      for (int kk = 0; kk < 2; ++kk)
        acc[m + 4][2] = __builtin_amdgcn_mfma_f32_16x16x32_bf16(ahi[m][kk], b2v[kk], acc[m + 4][2], 0, 0, 0);
    __builtin_amdgcn_s_setprio(0);
    __builtin_amdgcn_s_barrier();
  }

  asm volatile("s_waitcnt vmcnt(0)");
#pragma unroll
  for (int m = 0; m < 8; ++m)
#pragma unroll
    for (int j = 0; j < 3; ++j)
#pragma unroll
      for (int r = 0; r < 4; ++r) {
        int row = m0 + wm + m * 16 + lg * 4 + r;
        int col = n0 + wn + j * 16 + l15;
        if constexpr (sizeof(OutT) == 2) C[(size_t)row * N + col] = (OutT)f2bf(acc[m][j][r]);
        else                             C[(size_t)row * N + col] = (OutT)acc[m][j][r];
      }
}

// ---------------- 2-phase 256x128 GEMM (o-proj): 16 MFMA per phase --------------- (r11)
template <typename OutT>
__global__ __launch_bounds__(512) void gemmOP(const ushort* __restrict__ A,
                                              const ushort* __restrict__ Bm,
                                              OutT* __restrict__ C,
                                              int M, int N, int K) {
  __shared__ __align__(16) ushort SM[49152];   // 96KB
  int nb = N >> 7;
  int bx = blockIdx.x % nb, by = blockIdx.x / nb;
  int m0 = by << 8, n0 = bx << 7;
  int tid = threadIdx.x;
  int lane = tid & 63, w = tid >> 6;
  int l15 = lane & 15, lg = lane >> 4;
  int wm = (w >> 2) * 128;
  int wn = (w & 3) * 32;
  int pA = (w >> 2);

  int srow = tid >> 3;
  int cb   = ((tid & 7) * 16) ^ ((srow & 7) << 4);
  const ushort* sA0 = A  + (size_t)(m0 + srow) * K + (cb >> 1);
  const ushort* sB0 = Bm + (size_t)(n0 + srow) * K + (cb >> 1);
  const ushort* srcs[3] = { sA0, sA0 + (size_t)128 * K, sB0 };
  size_t rstep = (size_t)64 * K;

  int nkt = K >> 6;

  auto STG = [&](int part, int t, int db) {
    ushort* d0 = SM + db * 24576 + part * 8192 + (w << 9);
    const ushort* s0 = srcs[part] + t * 64;
    async16(s0, d0);
    async16(s0 + rstep, d0 + 4096);
  };

  fv4 acc[8][2] = {};
  sv8 a[8][2], b[2][2];

#pragma unroll
  for (int p = 0; p < 3; ++p) STG(p, 0, 0);
  {
    int t1 = 1 < nkt ? 1 : 0;
#pragma unroll
    for (int p = 0; p < 3; ++p) STG(p, t1, 1);
  }
  asm volatile("s_waitcnt vmcnt(6)");
  __builtin_amdgcn_s_barrier();

  for (int t = 0; t < nkt; ++t) {
    int db = t & 1;
    int t2 = t + 2 < nkt ? t + 2 : nkt - 1;
    const char* Ab = (const char*)SM + db * 49152 + pA * 16384;
    const char* Bb = (const char*)SM + db * 49152 + 32768;

    // ---- P1: read all A (16) + B j0,j1 (4); MFMA A-lo x {j0,j1} ----
#pragma unroll
    for (int m = 0; m < 8; ++m)
#pragma unroll
      for (int kk = 0; kk < 2; ++kk) {
        int row = m * 16 + l15;
        a[m][kk] = *(const sv8*)(Ab + row * 128 + ((kk * 64 + lg * 16) ^ ((row & 7) << 4)));
      }
#pragma unroll
    for (int j = 0; j < 2; ++j)
#pragma unroll
      for (int kk = 0; kk < 2; ++kk) {
        int row = wn + j * 16 + l15;
        b[j][kk] = *(const sv8*)(Bb + row * 128 + ((kk * 64 + lg * 16) ^ ((row & 7) << 4)));
      }
    __builtin_amdgcn_s_barrier();
    asm volatile("s_waitcnt lgkmcnt(0)");
    __builtin_amdgcn_s_setprio(1);
#pragma unroll
    for (int m = 0; m < 4; ++m)
#pragma unroll
      for (int j = 0; j < 2; ++j)
#pragma unroll
        for (int kk = 0; kk < 2; ++kk)
          acc[m][j] = __builtin_amdgcn_mfma_f32_16x16x32_bf16(a[m][kk], b[j][kk], acc[m][j], 0, 0, 0);
    __builtin_amdgcn_s_setprio(0);
    __builtin_amdgcn_s_barrier();

    // ---- P2: stage T+2 (6 loads); vmcnt(6) -> T+1 landed; MFMA A-hi x {j0,j1} ----
    STG(0, t2, db);
    STG(1, t2, db);
    STG(2, t2, db);
    asm volatile("s_waitcnt vmcnt(6)");
    __builtin_amdgcn_s_barrier();
    __builtin_amdgcn_s_setprio(1);
#pragma unroll
    for (int m = 0; m < 4; ++m)
#pragma unroll
      for (int j = 0; j < 2; ++j)
#pragma unroll
        for (int kk = 0; kk < 2; ++kk)
          acc[m + 4][j] = __builtin_amdgcn_mfma_f32_16x16x32_bf16(a[m + 4][kk], b[j][kk], acc[m + 4][j], 0, 0, 0);
    __builtin_amdgcn_s_setprio(0);
    __builtin_amdgcn_s_barrier();
  }

  asm volatile("s_waitcnt vmcnt(0)");
#pragma unroll
  for (int m = 0; m < 8; ++m)
#pragma unroll
    for (int j = 0; j < 2; ++j)
#pragma unroll
      for (int r = 0; r < 4; ++r) {
        int row = m0 + wm + m * 16 + lg * 4 + r;
        int col = n0 + wn + j * 16 + l15;
        if constexpr (sizeof(OutT) == 2) C[(size_t)row * N + col] = (OutT)f2bf(acc[m][j][r]);
        else                             C[(size_t)row * N + col] = (OutT)acc[m][j][r];
      }
}

// ---------------- Flash attention (causal, GQA) ---------------- (r11 verbatim)
// 512 thr = 8 waves; two 4-wave halves k-split one q-tile; dbuf K/V in LDS;
// K 16-slot swizzle, V 64x256B layout; in-LDS f32 merge; 2 passes (pr, 15-pr).
__global__ __launch_bounds__(512, 2) void attn_kernel(const ushort* __restrict__ Q,
                                                      const ushort* __restrict__ Kr,
                                                      const ushort* __restrict__ Vt,
                                                      ushort* __restrict__ O) {
  __shared__ __align__(16) ushort SMEM[65536];   // 128KB

  int blk = blockIdx.x;
  int bh  = blk & 31;
  int pr  = blk >> 5;
  int h   = bh & 15;
  int b   = bh >> 4;
  int kv  = h >> 2;
  int lane = threadIdx.x & 63, w = threadIdx.x >> 6;
  int wg = w & 3, Hf = w >> 2;
  int l31 = lane & 31, hh = lane >> 5;

  const ushort* Qbase = Q  + (size_t)(b * NH  + h ) * S_ * HD;
  const ushort* Kbase = Kr + (size_t)(b * NKV + kv) * S_ * HD;
  const ushort* Vbase = Vt + (size_t)(b * NKV + kv) * HD * S_;

  const ushort* kSrc[4]; ushort* kDst[2][4];
  const ushort* vSrc[4]; ushort* vDst[2][4];
#pragma unroll
  for (int it = 0; it < 4; ++it) {
    int lin = it * 4096 + wg * 1024 + lane * 16;
    { int row = lin >> 8; int cbv = (lin & 255) ^ ((row & 15) << 4);
      kSrc[it] = Kbase + (size_t)row * HD + (cbv >> 1); }
    { int row = lin >> 8; int cp = lin & 255; int cl = cp ^ ((row & 15) << 4);
      int d = row + ((cl >> 7) << 6);       // half-bit -> +64 d
      int koff = (cl & 127) >> 1;
      vSrc[it] = Vbase + (size_t)d * S_ + koff; }
#pragma unroll
    for (int buf = 0; buf < 2; ++buf) {
      kDst[buf][it] = SMEM + Hf * 16384 + buf * 8192 + ((it * 4096 + wg * 1024) >> 1);
      vDst[buf][it] = SMEM + 32768 + Hf * 16384 + buf * 8192 + ((it * 4096 + wg * 1024) >> 1);
    }
  }

  float* cML = (float*)SMEM;
  float* cO  = (float*)SMEM + 512;

  for (int pass = 0; pass < 2; ++pass) {
    int qt = pass ? (15 - pr) : pr;
    int q0 = qt << 7;
    int qrow_w = q0 + wg * 32;
    int myq    = qrow_w + l31;
    int nj     = qt + 1;
    int ktbase = Hf * nj;

    sv8 qf[8];
#pragma unroll
    for (int kk = 0; kk < 8; ++kk)
      qf[kk] = *(const sv8*)(Qbase + (size_t)myq * HD + kk * 16 + hh * 8);

    fv16 oacc[4] = {};
    float mrun = -1e30f, lrun = 0.f;

    {
      size_t k0 = (size_t)ktbase << 6;
#pragma unroll
      for (int it = 0; it < 4; ++it) async16(kSrc[it] + k0 * HD, kDst[0][it]);
#pragma unroll
      for (int it = 0; it < 4; ++it) async16(vSrc[it] + k0,      vDst[0][it]);
    }

    for (int j = 0; j < nj; ++j) {
      int cur = j & 1, nxt = cur ^ 1;
      __syncthreads();
      if (j + 1 < nj) {
        size_t k0n = (size_t)(ktbase + j + 1) << 6;
#pragma unroll
        for (int it = 0; it < 4; ++it) async16(kSrc[it] + k0n * HD, kDst[nxt][it]);
#pragma unroll
        for (int it = 0; it < 4; ++it) async16(vSrc[it] + k0n,      vDst[nxt][it]);
      }
      const char* KsC = (const char*)(SMEM + Hf * 16384 + cur * 8192);
      const char* VsC = (const char*)(SMEM + 32768 + Hf * 16384 + cur * 8192);
      int k0 = (ktbase + j) << 6;

      fv16 sacc[2] = {};
      __builtin_amdgcn_s_setprio(1);
#pragma unroll
      for (int kk = 0; kk < 8; ++kk) {
        int cbq = kk * 32 + hh * 16;
        int r0 = l31, r1 = 32 + l31;
        sv8 kf0 = *(const sv8*)(KsC + r0 * 256 + (cbq ^ ((r0 & 15) << 4)));
        sv8 kf1 = *(const sv8*)(KsC + r1 * 256 + (cbq ^ ((r1 & 15) << 4)));
        sacc[0] = __builtin_amdgcn_mfma_f32_32x32x16_bf16(kf0, qf[kk], sacc[0], 0, 0, 0);
        sacc[1] = __builtin_amdgcn_mfma_f32_32x32x16_bf16(kf1, qf[kk], sacc[1], 0, 0, 0);
      }
      __builtin_amdgcn_s_setprio(0);

      if (k0 + 63 > qrow_w) {
        int thr = myq - k0 - 4 * hh;
#pragma unroll
        for (int t = 0; t < 2; ++t)
#pragma unroll
          for (int r = 0; r < 16; ++r) {
            int kp = t * 32 + (r & 3) + 8 * (r >> 2);
            if (kp > thr) sacc[t][r] = -1e38f;
          }
      }

      float tmax = fmaxf(tmax16(sacc[0]), tmax16(sacc[1]));
      tmax = fmaxf(tmax, __shfl_xor(tmax, 32, 64));

      if (__any(tmax > mrun + 8.0f)) {
        float mnew = fmaxf(mrun, tmax);
        float esc  = fast_exp2(mrun - mnew);
        lrun *= esc;
        float er[16];
#pragma unroll
        for (int r = 0; r < 16; ++r) er[r] = __shfl(esc, (r & 3) + 8 * (r >> 2) + 4 * hh, 64);
#pragma unroll
        for (int d0 = 0; d0 < 4; ++d0)
#pragma unroll
          for (int r = 0; r < 16; ++r) oacc[d0][r] *= er[r];
        mrun = mnew;
      }

#pragma unroll
      for (int t = 0; t < 2; ++t)
#pragma unroll
        for (int r = 0; r < 16; ++r) sacc[t][r] = fast_exp2(sacc[t][r] - mrun);
      float psum = tsum16(sacc[0]) + tsum16(sacc[1]);
      psum += __shfl_xor(psum, 32, 64);
      lrun += psum;

      union Frag { unsigned int u[4]; sv8 v; } pa[4];
#pragma unroll
      for (int t = 0; t < 2; ++t)
#pragma unroll
        for (int half = 0; half < 2; ++half) {
          int cbq = half * 8;
          unsigned int a0 = cvtpk(sacc[t][cbq + 0], sacc[t][cbq + 1]);
          unsigned int a1 = cvtpk(sacc[t][cbq + 2], sacc[t][cbq + 3]);
          unsigned int b0 = cvtpk(sacc[t][cbq + 4], sacc[t][cbq + 5]);
          unsigned int b1 = cvtpk(sacc[t][cbq + 6], sacc[t][cbq + 7]);
          unsigned int a0p = xhalf(a0), a1p = xhalf(a1);
          unsigned int b0p = xhalf(b0), b1p = xhalf(b1);
          pa[2 * t + half].u[0] = hh ? b0p : a0;
          pa[2 * t + half].u[1] = hh ? b1p : a1;
          pa[2 * t + half].u[2] = hh ? b0  : a0p;
          pa[2 * t + half].u[3] = hh ? b1  : a1p;
        }

      __builtin_amdgcn_s_setprio(1);
#pragma unroll
      for (int ks = 0; ks < 4; ++ks) {
#pragma unroll
        for (int d0 = 0; d0 < 4; ++d0) {
          int d = d0 * 32 + l31;
          int row = d & 63;
          int cl = ((d >> 6) << 7) + ks * 32 + hh * 16;
          sv8 vf = *(const sv8*)(VsC + row * 256 + (cl ^ ((row & 15) << 4)));
          oacc[d0] = __builtin_amdgcn_mfma_f32_32x32x16_bf16(pa[ks].v, vf, oacc[d0], 0, 0, 0);
        }
      }
      __builtin_amdgcn_s_setprio(0);
    }

    __syncthreads();
    if (Hf) {
      int base = wg * 64 + lane;
      cML[base * 2]     = mrun;
      cML[base * 2 + 1] = lrun;
      float* dst = cO + base * 65;
#pragma unroll
      for (int d0 = 0; d0 < 4; ++d0)
#pragma unroll
        for (int r = 0; r < 16; ++r) dst[d0 * 16 + r] = oacc[d0][r];
    }
    __syncthreads();
    if (!Hf) {
      int base = wg * 64 + lane;
      float m2 = cML[base * 2], l2 = cML[base * 2 + 1];
      const float* src = cO + base * 65;
      float m  = fmaxf(mrun, m2);
      float e1 = fast_exp2(mrun - m), e2 = fast_exp2(m2 - m);
      float l  = lrun * e1 + l2 * e2;
      float inv = 1.0f / l;
      float f1 = e1 * inv, f2 = e2 * inv;
      float f1b[16], f2b[16];
#pragma unroll
      for (int r = 0; r < 16; ++r) {
        int ro = (r & 3) + 8 * (r >> 2) + 4 * hh;
        f1b[r] = __shfl(f1, ro, 64);
        f2b[r] = __shfl(f2, ro, 64);
      }
#pragma unroll
      for (int r = 0; r < 16; ++r) {
        int q = qrow_w + (r & 3) + 8 * (r >> 2) + 4 * hh;
#pragma unroll
        for (int d0 = 0; d0 < 4; ++d0) {
          int d = d0 * 32 + l31;
          float val = oacc[d0][r] * f1b[r] + src[d0 * 16 + r] * f2b[r];
          O[(size_t)(b * S_ + q) * DIM_ + h * HD + d] = f2bf(val);
        }
      }
    }
    __syncthreads();
  }
}

// ---------------- host launcher ----------------
extern "C" void kernel_launch(void* const* d_in, const int* in_sizes, int n_in,
                              void* d_out, int out_size, void* d_ws, size_t ws_size,
                              hipStream_t stream) {
  const float* x  = (const float*)d_in[0];
  const float* wq = (const float*)d_in[1];
  const float* wk = (const float*)d_in[2];
  const float* wv = (const float*)d_in[3];
  const float* wo = (const float*)d_in[4];
  const float* fc = (const float*)d_in[5];
  const float* fs = (const float*)d_in[6];
  float* out = (float*)d_out;

  char* ws = (char*)d_ws;
  size_t off = 0;
  auto alloc = [&](size_t bytes) -> ushort* {
    ushort* p = (ushort*)(ws + off);
    off += (bytes + 255) & ~(size_t)255;
    return p;
  };
  ushort* xb    = alloc((size_t)B_ * S_ * DIM_ * 2);        // 16.8MB
  ushort* wqkvb = alloc((size_t)QKVN * DIM_ * 2);           // 12.6MB
  ushort* wob   = alloc((size_t)DIM_ * DIM_ * 2);           // 8MB
  ushort* qkvr  = alloc((size_t)B_ * S_ * QKVN * 2);        // 25.2MB
  ushort* qr    = alloc((size_t)B_ * S_ * DIM_ * 2);        // 16MB
  ushort* kr    = alloc((size_t)B_ * S_ * NKV * HD * 2);    // 4MB
  ushort* vtb   = alloc((size_t)B_ * S_ * NKV * HD * 2);    // 4MB
  ushort* obf   = alloc((size_t)B_ * S_ * DIM_ * 2);        // 16MB
  (void)ws_size; (void)n_in; (void)in_sizes; (void)out_size;

  // all f32->bf16 converts in ONE launch (x + wq|wk|wv + wo)
  const int cvt_elems = 2 * DIM_ * DIM_ /*x*/ + 2 * DIM_ * DIM_ /*wq+wo*/
                      + 2 * NKV * HD * DIM_ /*wk+wv*/;
  cvtall_kernel<<<cvt_elems / 1024, 256, 0, stream>>>(x, wq, wk, wv, wo, xb, wqkvb, wob);

  // fused QKV projection: [4096, 2048] x [3072, 2048]^T -> [4096, 3072] (4-phase 256x192)
  gemm192<ushort><<<(B_ * S_ / 256) * (QKVN / 192), 512, 0, stream>>>(xb, wqkvb, qkvr,
                                                                     B_ * S_, QKVN, DIM_);

  // rope Q+K (no-LDS, full occupancy) and V transpose as separate launches
  const float qscale = 0.08838834764831845f * 1.4426950408889634f;
  rope2_kernel<<<(B_ * S_ * 20 * 16) / 256, 256, 0, stream>>>(qkvr, fc, fs, qr, kr, qscale);
  vtrans_kernel<<<B_ * NKV * (S_ / 128), 256, 0, stream>>>(qkvr + 2560, vtb, QKVN);

  // attention: 256 blocks x 512 thr; uniform 17-tile chains per wave (k-split + pair)
  attn_kernel<<<B_ * NH * 8, 512, 0, stream>>>(qr, kr, vtb, obf);

  // output projection -> f32 d_out (2-phase 256x128 tiles, 256 blocks = 1/CU)
  gemmOP<float><<<(B_ * S_ / 256) * (DIM_ / 128), 512, 0, stream>>>(obf, wob, out, B_ * S_, DIM_, DIM_);
}

// Round 17
// 178.604 us; speedup vs baseline: 2.0179x; 1.0117x over previous
//
#include <hip/hip_runtime.h>
#include <hip/hip_bf16.h>

// Problem constants
#define B_   2
#define S_   2048
#define DIM_ 2048
#define NH   16
#define NKV  4
#define HD   128
#define QKVN 3072   // fused projection width: 2048 (Q) + 512 (K) + 512 (V)

typedef __attribute__((ext_vector_type(8)))  short  sv8;   // 8 x bf16 (MFMA operand)
typedef __attribute__((ext_vector_type(8)))  ushort usv8;
typedef __attribute__((ext_vector_type(4)))  float  fv4;
typedef __attribute__((ext_vector_type(16))) float  fv16;

__device__ __forceinline__ float fast_exp2(float x) {
  return __builtin_amdgcn_exp2f(x);   // v_exp_f32 (base-2)
}

__device__ __forceinline__ ushort f2bf(float f) {
  __hip_bfloat16 h = __float2bfloat16(f);
  union { __hip_bfloat16 h; ushort u; } c; c.h = h; return c.u;
}
__device__ __forceinline__ float bf2f(ushort u) {
  union { unsigned int i; float f; } c; c.i = ((unsigned)u) << 16; return c.f;
}

// pack two f32 -> two bf16 in one u32 (possibly RTZ — only for MFMA operands)
__device__ __forceinline__ unsigned int cvtpk(float lo, float hi) {
  unsigned int r;
  asm("v_cvt_pk_bf16_f32 %0, %1, %2" : "=v"(r) : "v"(lo), "v"(hi));
  return r;
}
// exchange with partner lane (lane ^ 32)
__device__ __forceinline__ unsigned int xhalf(unsigned int x) {
  return (unsigned int)__shfl_xor((int)x, 32, 64);
}

// tree reductions over a 16-vector (depth 5, ILP-friendly)
__device__ __forceinline__ float tmax16(const fv16& v) {
  float a = fmaxf(fmaxf(v[0], v[1]),  fmaxf(v[2], v[3]));
  float b = fmaxf(fmaxf(v[4], v[5]),  fmaxf(v[6], v[7]));
  float c = fmaxf(fmaxf(v[8], v[9]),  fmaxf(v[10], v[11]));
  float d = fmaxf(fmaxf(v[12], v[13]), fmaxf(v[14], v[15]));
  return fmaxf(fmaxf(a, b), fmaxf(c, d));
}
__device__ __forceinline__ float tsum16(const fv16& v) {
  float a = (v[0] + v[1]) + (v[2] + v[3]);
  float b = (v[4] + v[5]) + (v[6] + v[7]);
  float c = (v[8] + v[9]) + (v[10] + v[11]);
  float d = (v[12] + v[13]) + (v[14] + v[15]);
  return (a + b) + (c + d);
}

// async global->LDS, 16B per lane; LDS dest is wave-uniform base (HW adds lane*16).
__device__ __forceinline__ void async16(const void* g, void* l) {
  __builtin_amdgcn_global_load_lds(
      (const __attribute__((address_space(1))) unsigned int*)g,
      (__attribute__((address_space(3))) unsigned int*)l, 16, 0, 0);
}

// ---------------- fused f32->bf16 convert: x, then wq|wk|wv -> wqkvb, wo -> wob ----
__global__ void cvtall_kernel(const float* __restrict__ x,
                              const float* __restrict__ wq, const float* __restrict__ wk,
                              const float* __restrict__ wv, const float* __restrict__ wo,
                              ushort* __restrict__ xb,
                              ushort* __restrict__ wqkvb, ushort* __restrict__ wob) {
  const int NX = 2 * 2048 * 2048;                 // x elems
  const int NQ = 2048 * 2048, NK = 512 * 2048;    // weight ranges (1024-aligned)
  int i = (blockIdx.x * 256 + threadIdx.x) * 4;
  const float* src; ushort* dst;
  if (i < NX) { src = x + i; dst = xb + i; }
  else {
    int j = i - NX;
    if (j < NQ)               { src = wq + j;             dst = wqkvb + j; }
    else if (j < NQ + NK)     { src = wk + (j - NQ);      dst = wqkvb + j; }
    else if (j < NQ + 2 * NK) { src = wv + (j - NQ - NK); dst = wqkvb + j; }
    else                      { int k = j - (NQ + 2 * NK); src = wo + k; dst = wob + k; }
  }
  fv4 v = *(const fv4*)src;
  ushort4 o;
  o.x = f2bf(v[0]); o.y = f2bf(v[1]); o.z = f2bf(v[2]); o.w = f2bf(v[3]);
  *(ushort4*)dst = o;
}

// ---------------- V transpose: rows of fused qkv -> (B,KVH,HD,S) ----------------
__global__ __launch_bounds__(256) void vtrans_kernel(const ushort* __restrict__ vraw,
                                                     ushort* __restrict__ vt, int rowstride) {
  __shared__ ushort tile[128][136];
  int blk = blockIdx.x;            // (b*NKV+kv)*16 + st
  int st  = blk & 15;
  int kvb = blk >> 4;
  int kv  = kvb & 3;
  int b   = kvb >> 2;
  int s0  = st << 7;
#pragma unroll
  for (int it = 0; it < 8; ++it) {
    int t = it * 256 + threadIdx.x;
    int srow = t >> 4;
    int d8 = (t & 15) * 8;
    usv8 v = *(const usv8*)(vraw + (size_t)(b * S_ + s0 + srow) * rowstride + kv * HD + d8);
#pragma unroll
    for (int j = 0; j < 8; ++j) tile[d8 + j][srow] = v[j];
  }
  __syncthreads();
#pragma unroll
  for (int it = 0; it < 8; ++it) {
    int t = it * 256 + threadIdx.x;
    int d = t >> 4;
    int s8 = (t & 15) * 8;
    usv8 o;
#pragma unroll
    for (int j = 0; j < 8; ++j) o[j] = tile[d][s8 + j];
    *(usv8*)(vt + ((size_t)(b * NKV + kv) * HD + d) * S_ + s0 + s8) = o;
  }
}

// ---------------- 4-phase 256x192 GEMM (QKV) with fused RoPE epilogue ----------------
// Main loop identical to r11's gemm192. Epilogue: Q/K cols get RoPE applied via
// lane-pair shfl (col parity == lane parity; 16-col j-blocks never straddle the
// 2048/2560 region boundaries -> branches lane-uniform) and are written directly
// to qr/kr in (B, heads, S, HD) layout; V cols go to qkvr for vtrans.
__global__ __launch_bounds__(512) void gemm192_rope(const ushort* __restrict__ A,
                                                    const ushort* __restrict__ Bm,
                                                    const float* __restrict__ fc,
                                                    const float* __restrict__ fs,
                                                    ushort* __restrict__ qr,
                                                    ushort* __restrict__ kr,
                                                    ushort* __restrict__ Cv,
                                                    float qscale,
                                                    int M, int N, int K) {
  __shared__ __align__(16) ushort SM[57344];   // 112KB
  int nb = N / 192;
  int bx = blockIdx.x % nb, by = blockIdx.x / nb;
  int m0 = by << 8;
  int n0 = bx * 192;
  int tid = threadIdx.x;
  int lane = tid & 63, w = tid >> 6;
  int l15 = lane & 15, lg = lane >> 4;
  int wm = (w >> 2) * 128;
  int wn = (w & 3) * 48;
  int pA = w >> 2;

  int srow = tid >> 3;
  int cb   = ((tid & 7) * 16) ^ ((srow & 7) << 4);
  const ushort* sA = A  + (size_t)(m0 + srow) * K + (cb >> 1);
  const ushort* sB = Bm + (size_t)(n0 + srow) * K + (cb >> 1);
  size_t rstep = (size_t)64 * K;
  int nkt = K >> 6;

  auto STG_A = [&](int t, int db) {
    ushort* base = SM + db * 28672 + (w << 9);
    const ushort* a0 = sA + (size_t)t * 64;
    async16(a0,             base);
    async16(a0 + rstep,     base + 4096);
    async16(a0 + 2 * rstep, base + 8192);
    async16(a0 + 3 * rstep, base + 12288);
  };
  auto STG_B = [&](int t, int db) {
    ushort* base = SM + db * 28672 + 16384 + (w << 9);
    const ushort* b0 = sB + (size_t)t * 64;
    async16(b0,             base);
    async16(b0 + rstep,     base + 4096);
    async16(b0 + 2 * rstep, base + 8192);
  };

  fv4 acc[8][3] = {};
  sv8 alo[4][2], ahi[4][2], b01[2][2], b2v[2];

  STG_A(0, 0); STG_B(0, 0);
  { int t1 = nkt > 1 ? 1 : 0; STG_A(t1, 1); STG_B(t1, 1); }
  asm volatile("s_waitcnt vmcnt(7)");
  __builtin_amdgcn_s_barrier();

  for (int t = 0; t < nkt; ++t) {
    int db = t & 1;
    int t2 = t + 2 < nkt ? t + 2 : nkt - 1;
    const char* Ab = (const char*)(SM + db * 28672) + pA * 16384;
    const char* Bb = (const char*)(SM + db * 28672) + 32768;

    // ---- P1: read A-lo(8) + B j0,j1(4); MFMA A-lo x {j0,j1} ----
#pragma unroll
    for (int m = 0; m < 4; ++m)
#pragma unroll
      for (int kk = 0; kk < 2; ++kk) {
        int row = m * 16 + l15;
        alo[m][kk] = *(const sv8*)(Ab + row * 128 + ((kk * 64 + lg * 16) ^ ((row & 7) << 4)));
      }
#pragma unroll
    for (int j = 0; j < 2; ++j)
#pragma unroll
      for (int kk = 0; kk < 2; ++kk) {
        int row = wn + j * 16 + l15;
        b01[j][kk] = *(const sv8*)(Bb + row * 128 + ((kk * 64 + lg * 16) ^ ((row & 7) << 4)));
      }
    __builtin_amdgcn_s_barrier();
    asm volatile("s_waitcnt lgkmcnt(0)");
    __builtin_amdgcn_s_setprio(1);
#pragma unroll
    for (int m = 0; m < 4; ++m)
#pragma unroll
      for (int j = 0; j < 2; ++j)
#pragma unroll
        for (int kk = 0; kk < 2; ++kk)
          acc[m][j] = __builtin_amdgcn_mfma_f32_16x16x32_bf16(alo[m][kk], b01[j][kk], acc[m][j], 0, 0, 0);
    __builtin_amdgcn_s_setprio(0);
    __builtin_amdgcn_s_barrier();

    // ---- P2: read A-hi(8) + B j2(2); MFMA A-lo x j2 ----
#pragma unroll
    for (int m = 0; m < 4; ++m)
#pragma unroll
      for (int kk = 0; kk < 2; ++kk) {
        int row = 64 + m * 16 + l15;
        ahi[m][kk] = *(const sv8*)(Ab + row * 128 + ((kk * 64 + lg * 16) ^ ((row & 7) << 4)));
      }
#pragma unroll
    for (int kk = 0; kk < 2; ++kk) {
      int row = wn + 32 + l15;
      b2v[kk] = *(const sv8*)(Bb + row * 128 + ((kk * 64 + lg * 16) ^ ((row & 7) << 4)));
    }
    __builtin_amdgcn_s_barrier();
    asm volatile("s_waitcnt lgkmcnt(0)");
    __builtin_amdgcn_s_setprio(1);
#pragma unroll
    for (int m = 0; m < 4; ++m)
#pragma unroll
      for (int kk = 0; kk < 2; ++kk)
        acc[m][2] = __builtin_amdgcn_mfma_f32_16x16x32_bf16(alo[m][kk], b2v[kk], acc[m][2], 0, 0, 0);
    __builtin_amdgcn_s_setprio(0);
    __builtin_amdgcn_s_barrier();

    // ---- P3: stage A(T+2); MFMA A-hi x {j0,j1} ----
    STG_A(t2, db);
    __builtin_amdgcn_s_barrier();
    __builtin_amdgcn_s_setprio(1);
#pragma unroll
    for (int m = 0; m < 4; ++m)
#pragma unroll
      for (int j = 0; j < 2; ++j)
#pragma unroll
        for (int kk = 0; kk < 2; ++kk)
          acc[m + 4][j] = __builtin_amdgcn_mfma_f32_16x16x32_bf16(ahi[m][kk], b01[j][kk], acc[m + 4][j], 0, 0, 0);
    __builtin_amdgcn_s_setprio(0);
    __builtin_amdgcn_s_barrier();

    // ---- P4: stage B(T+2); vmcnt(7) -> T+1 landed; MFMA A-hi x j2 ----
    STG_B(t2, db);
    asm volatile("s_waitcnt vmcnt(7)");
    __builtin_amdgcn_s_barrier();
    __builtin_amdgcn_s_setprio(1);
#pragma unroll
    for (int m = 0; m < 4; ++m)
#pragma unroll
      for (int kk = 0; kk < 2; ++kk)
        acc[m + 4][2] = __builtin_amdgcn_mfma_f32_16x16x32_bf16(ahi[m][kk], b2v[kk], acc[m + 4][2], 0, 0, 0);
    __builtin_amdgcn_s_setprio(0);
    __builtin_amdgcn_s_barrier();
  }

  // ---- epilogue: RoPE-fused write ----
  asm volatile("s_waitcnt vmcnt(0)");
  int lpar = lane & 1;
#pragma unroll
  for (int m = 0; m < 8; ++m)
#pragma unroll
    for (int j = 0; j < 3; ++j) {
      int col = n0 + wn + j * 16 + l15;
      if (col >= 2560) {
        // V: to qkvr (vtrans consumes)
#pragma unroll
        for (int r = 0; r < 4; ++r) {
          int row = m0 + wm + m * 16 + lg * 4 + r;
          Cv[(size_t)row * QKVN + col] = f2bf(acc[m][j][r]);
        }
      } else {
        bool isQ  = col < 2048;
        int hcol  = isQ ? col : col - 2048;
        int hidx  = hcol >> 7;
        int d     = col & 127;
        int dp    = d >> 1;
        float scale = isQ ? qscale : 1.0f;
        ushort* base = isQ ? qr : kr;
        int heads = isQ ? NH : NKV;
#pragma unroll
        for (int r = 0; r < 4; ++r) {
          int row = m0 + wm + m * 16 + lg * 4 + r;
          int s   = row & (S_ - 1);
          int bb  = row >> 11;
          float val = acc[m][j][r];
          float pv  = __shfl_xor(val, 1, 64);
          float c   = fc[s * 64 + dp];
          float sn  = fs[s * 64 + dp];
          float outv = (lpar ? (pv * sn + val * c) : (val * c - pv * sn)) * scale;
          base[((size_t)(bb * heads + hidx) * S_ + s) * HD + d] = f2bf(outv);
        }
      }
    }
}

// ---------------- 2-phase 256x128 GEMM (o-proj): 16 MFMA per phase --------------- (r11)
template <typename OutT>
__global__ __launch_bounds__(512) void gemmOP(const ushort* __restrict__ A,
                                              const ushort* __restrict__ Bm,
                                              OutT* __restrict__ C,
                                              int M, int N, int K) {
  __shared__ __align__(16) ushort SM[49152];   // 96KB
  int nb = N >> 7;
  int bx = blockIdx.x % nb, by = blockIdx.x / nb;
  int m0 = by << 8, n0 = bx << 7;
  int tid = threadIdx.x;
  int lane = tid & 63, w = tid >> 6;
  int l15 = lane & 15, lg = lane >> 4;
  int wm = (w >> 2) * 128;
  int wn = (w & 3) * 32;
  int pA = (w >> 2);

  int srow = tid >> 3;
  int cb   = ((tid & 7) * 16) ^ ((srow & 7) << 4);
  const ushort* sA0 = A  + (size_t)(m0 + srow) * K + (cb >> 1);
  const ushort* sB0 = Bm + (size_t)(n0 + srow) * K + (cb >> 1);
  const ushort* srcs[3] = { sA0, sA0 + (size_t)128 * K, sB0 };
  size_t rstep = (size_t)64 * K;

  int nkt = K >> 6;

  auto STG = [&](int part, int t, int db) {
    ushort* d0 = SM + db * 24576 + part * 8192 + (w << 9);
    const ushort* s0 = srcs[part] + t * 64;
    async16(s0, d0);
    async16(s0 + rstep, d0 + 4096);
  };

  fv4 acc[8][2] = {};
  sv8 a[8][2], b[2][2];

#pragma unroll
  for (int p = 0; p < 3; ++p) STG(p, 0, 0);
  {
    int t1 = 1 < nkt ? 1 : 0;
#pragma unroll
    for (int p = 0; p < 3; ++p) STG(p, t1, 1);
  }
  asm volatile("s_waitcnt vmcnt(6)");
  __builtin_amdgcn_s_barrier();

  for (int t = 0; t < nkt; ++t) {
    int db = t & 1;
    int t2 = t + 2 < nkt ? t + 2 : nkt - 1;
    const char* Ab = (const char*)SM + db * 49152 + pA * 16384;
    const char* Bb = (const char*)SM + db * 49152 + 32768;

    // ---- P1: read all A (16) + B j0,j1 (4); MFMA A-lo x {j0,j1} ----
#pragma unroll
    for (int m = 0; m < 8; ++m)
#pragma unroll
      for (int kk = 0; kk < 2; ++kk) {
        int row = m * 16 + l15;
        a[m][kk] = *(const sv8*)(Ab + row * 128 + ((kk * 64 + lg * 16) ^ ((row & 7) << 4)));
      }
#pragma unroll
    for (int j = 0; j < 2; ++j)
#pragma unroll
      for (int kk = 0; kk < 2; ++kk) {
        int row = wn + j * 16 + l15;
        b[j][kk] = *(const sv8*)(Bb + row * 128 + ((kk * 64 + lg * 16) ^ ((row & 7) << 4)));
      }
    __builtin_amdgcn_s_barrier();
    asm volatile("s_waitcnt lgkmcnt(0)");
    __builtin_amdgcn_s_setprio(1);
#pragma unroll
    for (int m = 0; m < 4; ++m)
#pragma unroll
      for (int j = 0; j < 2; ++j)
#pragma unroll
        for (int kk = 0; kk < 2; ++kk)
          acc[m][j] = __builtin_amdgcn_mfma_f32_16x16x32_bf16(a[m][kk], b[j][kk], acc[m][j], 0, 0, 0);
    __builtin_amdgcn_s_setprio(0);
    __builtin_amdgcn_s_barrier();

    // ---- P2: stage T+2 (6 loads); vmcnt(6) -> T+1 landed; MFMA A-hi x {j0,j1} ----
    STG(0, t2, db);
    STG(1, t2, db);
    STG(2, t2, db);
    asm volatile("s_waitcnt vmcnt(6)");
    __builtin_amdgcn_s_barrier();
    __builtin_amdgcn_s_setprio(1);
#pragma unroll
    for (int m = 0; m < 4; ++m)
#pragma unroll
      for (int j = 0; j < 2; ++j)
#pragma unroll
        for (int kk = 0; kk < 2; ++kk)
          acc[m + 4][j] = __builtin_amdgcn_mfma_f32_16x16x32_bf16(a[m + 4][kk], b[j][kk], acc[m + 4][j], 0, 0, 0);
    __builtin_amdgcn_s_setprio(0);
    __builtin_amdgcn_s_barrier();
  }

  asm volatile("s_waitcnt vmcnt(0)");
#pragma unroll
  for (int m = 0; m < 8; ++m)
#pragma unroll
    for (int j = 0; j < 2; ++j)
#pragma unroll
      for (int r = 0; r < 4; ++r) {
        int row = m0 + wm + m * 16 + lg * 4 + r;
        int col = n0 + wn + j * 16 + l15;
        if constexpr (sizeof(OutT) == 2) C[(size_t)row * N + col] = (OutT)f2bf(acc[m][j][r]);
        else                             C[(size_t)row * N + col] = (OutT)acc[m][j][r];
      }
}

// ---------------- Flash attention (causal, GQA) ---------------- (r11 verbatim)
// 512 thr = 8 waves; two 4-wave halves k-split one q-tile; dbuf K/V in LDS;
// K 16-slot swizzle, V 64x256B layout; in-LDS f32 merge; 2 passes (pr, 15-pr).
__global__ __launch_bounds__(512, 2) void attn_kernel(const ushort* __restrict__ Q,
                                                      const ushort* __restrict__ Kr,
                                                      const ushort* __restrict__ Vt,
                                                      ushort* __restrict__ O) {
  __shared__ __align__(16) ushort SMEM[65536];   // 128KB

  int blk = blockIdx.x;
  int bh  = blk & 31;
  int pr  = blk >> 5;
  int h   = bh & 15;
  int b   = bh >> 4;
  int kv  = h >> 2;
  int lane = threadIdx.x & 63, w = threadIdx.x >> 6;
  int wg = w & 3, Hf = w >> 2;
  int l31 = lane & 31, hh = lane >> 5;

  const ushort* Qbase = Q  + (size_t)(b * NH  + h ) * S_ * HD;
  const ushort* Kbase = Kr + (size_t)(b * NKV + kv) * S_ * HD;
  const ushort* Vbase = Vt + (size_t)(b * NKV + kv) * HD * S_;

  const ushort* kSrc[4]; ushort* kDst[2][4];
  const ushort* vSrc[4]; ushort* vDst[2][4];
#pragma unroll
  for (int it = 0; it < 4; ++it) {
    int lin = it * 4096 + wg * 1024 + lane * 16;
    { int row = lin >> 8; int cbv = (lin & 255) ^ ((row & 15) << 4);
      kSrc[it] = Kbase + (size_t)row * HD + (cbv >> 1); }
    { int row = lin >> 8; int cp = lin & 255; int cl = cp ^ ((row & 15) << 4);
      int d = row + ((cl >> 7) << 6);       // half-bit -> +64 d
      int koff = (cl & 127) >> 1;
      vSrc[it] = Vbase + (size_t)d * S_ + koff; }
#pragma unroll
    for (int buf = 0; buf < 2; ++buf) {
      kDst[buf][it] = SMEM + Hf * 16384 + buf * 8192 + ((it * 4096 + wg * 1024) >> 1);
      vDst[buf][it] = SMEM + 32768 + Hf * 16384 + buf * 8192 + ((it * 4096 + wg * 1024) >> 1);
    }
  }

  float* cML = (float*)SMEM;
  float* cO  = (float*)SMEM + 512;

  for (int pass = 0; pass < 2; ++pass) {
    int qt = pass ? (15 - pr) : pr;
    int q0 = qt << 7;
    int qrow_w = q0 + wg * 32;
    int myq    = qrow_w + l31;
    int nj     = qt + 1;
    int ktbase = Hf * nj;

    sv8 qf[8];
#pragma unroll
    for (int kk = 0; kk < 8; ++kk)
      qf[kk] = *(const sv8*)(Qbase + (size_t)myq * HD + kk * 16 + hh * 8);

    fv16 oacc[4] = {};
    float mrun = -1e30f, lrun = 0.f;

    {
      size_t k0 = (size_t)ktbase << 6;
#pragma unroll
      for (int it = 0; it < 4; ++it) async16(kSrc[it] + k0 * HD, kDst[0][it]);
#pragma unroll
      for (int it = 0; it < 4; ++it) async16(vSrc[it] + k0,      vDst[0][it]);
    }

    for (int j = 0; j < nj; ++j) {
      int cur = j & 1, nxt = cur ^ 1;
      __syncthreads();
      if (j + 1 < nj) {
        size_t k0n = (size_t)(ktbase + j + 1) << 6;
#pragma unroll
        for (int it = 0; it < 4; ++it) async16(kSrc[it] + k0n * HD, kDst[nxt][it]);
#pragma unroll
        for (int it = 0; it < 4; ++it) async16(vSrc[it] + k0n,      vDst[nxt][it]);
      }
      const char* KsC = (const char*)(SMEM + Hf * 16384 + cur * 8192);
      const char* VsC = (const char*)(SMEM + 32768 + Hf * 16384 + cur * 8192);
      int k0 = (ktbase + j) << 6;

      fv16 sacc[2] = {};
      __builtin_amdgcn_s_setprio(1);
#pragma unroll
      for (int kk = 0; kk < 8; ++kk) {
        int cbq = kk * 32 + hh * 16;
        int r0 = l31, r1 = 32 + l31;
        sv8 kf0 = *(const sv8*)(KsC + r0 * 256 + (cbq ^ ((r0 & 15) << 4)));
        sv8 kf1 = *(const sv8*)(KsC + r1 * 256 + (cbq ^ ((r1 & 15) << 4)));
        sacc[0] = __builtin_amdgcn_mfma_f32_32x32x16_bf16(kf0, qf[kk], sacc[0], 0, 0, 0);
        sacc[1] = __builtin_amdgcn_mfma_f32_32x32x16_bf16(kf1, qf[kk], sacc[1], 0, 0, 0);
      }
      __builtin_amdgcn_s_setprio(0);

      if (k0 + 63 > qrow_w) {
        int thr = myq - k0 - 4 * hh;
#pragma unroll
        for (int t = 0; t < 2; ++t)
#pragma unroll
          for (int r = 0; r < 16; ++r) {
            int kp = t * 32 + (r & 3) + 8 * (r >> 2);
            if (kp > thr) sacc[t][r] = -1e38f;
          }
      }

      float tmax = fmaxf(tmax16(sacc[0]), tmax16(sacc[1]));
      tmax = fmaxf(tmax, __shfl_xor(tmax, 32, 64));

      if (__any(tmax > mrun + 8.0f)) {
        float mnew = fmaxf(mrun, tmax);
        float esc  = fast_exp2(mrun - mnew);
        lrun *= esc;
        float er[16];
#pragma unroll
        for (int r = 0; r < 16; ++r) er[r] = __shfl(esc, (r & 3) + 8 * (r >> 2) + 4 * hh, 64);
#pragma unroll
        for (int d0 = 0; d0 < 4; ++d0)
#pragma unroll
          for (int r = 0; r < 16; ++r) oacc[d0][r] *= er[r];
        mrun = mnew;
      }

#pragma unroll
      for (int t = 0; t < 2; ++t)
#pragma unroll
        for (int r = 0; r < 16; ++r) sacc[t][r] = fast_exp2(sacc[t][r] - mrun);
      float psum = tsum16(sacc[0]) + tsum16(sacc[1]);
      psum += __shfl_xor(psum, 32, 64);
      lrun += psum;

      union Frag { unsigned int u[4]; sv8 v; } pa[4];
#pragma unroll
      for (int t = 0; t < 2; ++t)
#pragma unroll
        for (int half = 0; half < 2; ++half) {
          int cbq = half * 8;
          unsigned int a0 = cvtpk(sacc[t][cbq + 0], sacc[t][cbq + 1]);
          unsigned int a1 = cvtpk(sacc[t][cbq + 2], sacc[t][cbq + 3]);
          unsigned int b0 = cvtpk(sacc[t][cbq + 4], sacc[t][cbq + 5]);
          unsigned int b1 = cvtpk(sacc[t][cbq + 6], sacc[t][cbq + 7]);
          unsigned int a0p = xhalf(a0), a1p = xhalf(a1);
          unsigned int b0p = xhalf(b0), b1p = xhalf(b1);
          pa[2 * t + half].u[0] = hh ? b0p : a0;
          pa[2 * t + half].u[1] = hh ? b1p : a1;
          pa[2 * t + half].u[2] = hh ? b0  : a0p;
          pa[2 * t + half].u[3] = hh ? b1  : a1p;
        }

      __builtin_amdgcn_s_setprio(1);
#pragma unroll
      for (int ks = 0; ks < 4; ++ks) {
#pragma unroll
        for (int d0 = 0; d0 < 4; ++d0) {
          int d = d0 * 32 + l31;
          int row = d & 63;
          int cl = ((d >> 6) << 7) + ks * 32 + hh * 16;
          sv8 vf = *(const sv8*)(VsC + row * 256 + (cl ^ ((row & 15) << 4)));
          oacc[d0] = __builtin_amdgcn_mfma_f32_32x32x16_bf16(pa[ks].v, vf, oacc[d0], 0, 0, 0);
        }
      }
      __builtin_amdgcn_s_setprio(0);
    }

    __syncthreads();
    if (Hf) {
      int base = wg * 64 + lane;
      cML[base * 2]     = mrun;
      cML[base * 2 + 1] = lrun;
      float* dst = cO + base * 65;
#pragma unroll
      for (int d0 = 0; d0 < 4; ++d0)
#pragma unroll
        for (int r = 0; r < 16; ++r) dst[d0 * 16 + r] = oacc[d0][r];
    }
    __syncthreads();
    if (!Hf) {
      int base = wg * 64 + lane;
      float m2 = cML[base * 2], l2 = cML[base * 2 + 1];
      const float* src = cO + base * 65;
      float m  = fmaxf(mrun, m2);
      float e1 = fast_exp2(mrun - m), e2 = fast_exp2(m2 - m);
      float l  = lrun * e1 + l2 * e2;
      float inv = 1.0f / l;
      float f1 = e1 * inv, f2 = e2 * inv;
      float f1b[16], f2b[16];
#pragma unroll
      for (int r = 0; r < 16; ++r) {
        int ro = (r & 3) + 8 * (r >> 2) + 4 * hh;
        f1b[r] = __shfl(f1, ro, 64);
        f2b[r] = __shfl(f2, ro, 64);
      }
#pragma unroll
      for (int r = 0; r < 16; ++r) {
        int q = qrow_w + (r & 3) + 8 * (r >> 2) + 4 * hh;
#pragma unroll
        for (int d0 = 0; d0 < 4; ++d0) {
          int d = d0 * 32 + l31;
          float val = oacc[d0][r] * f1b[r] + src[d0 * 16 + r] * f2b[r];
          O[(size_t)(b * S_ + q) * DIM_ + h * HD + d] = f2bf(val);
        }
      }
    }
    __syncthreads();
  }
}

// ---------------- host launcher ----------------
extern "C" void kernel_launch(void* const* d_in, const int* in_sizes, int n_in,
                              void* d_out, int out_size, void* d_ws, size_t ws_size,
                              hipStream_t stream) {
  const float* x  = (const float*)d_in[0];
  const float* wq = (const float*)d_in[1];
  const float* wk = (const float*)d_in[2];
  const float* wv = (const float*)d_in[3];
  const float* wo = (const float*)d_in[4];
  const float* fc = (const float*)d_in[5];
  const float* fs = (const float*)d_in[6];
  float* out = (float*)d_out;

  char* ws = (char*)d_ws;
  size_t off = 0;
  auto alloc = [&](size_t bytes) -> ushort* {
    ushort* p = (ushort*)(ws + off);
    off += (bytes + 255) & ~(size_t)255;
    return p;
  };
  ushort* xb    = alloc((size_t)B_ * S_ * DIM_ * 2);        // 16.8MB
  ushort* wqkvb = alloc((size_t)QKVN * DIM_ * 2);           // 12.6MB
  ushort* wob   = alloc((size_t)DIM_ * DIM_ * 2);           // 8MB
  ushort* qkvr  = alloc((size_t)B_ * S_ * QKVN * 2);        // 25.2MB (V region used)
  ushort* qr    = alloc((size_t)B_ * S_ * DIM_ * 2);        // 16MB
  ushort* kr    = alloc((size_t)B_ * S_ * NKV * HD * 2);    // 4MB
  ushort* vtb   = alloc((size_t)B_ * S_ * NKV * HD * 2);    // 4MB
  ushort* obf   = alloc((size_t)B_ * S_ * DIM_ * 2);        // 16MB
  (void)ws_size; (void)n_in; (void)in_sizes; (void)out_size;

  // all f32->bf16 converts in ONE launch (x + wq|wk|wv + wo)
  const int cvt_elems = 2 * DIM_ * DIM_ /*x*/ + 2 * DIM_ * DIM_ /*wq+wo*/
                      + 2 * NKV * HD * DIM_ /*wk+wv*/;
  cvtall_kernel<<<cvt_elems / 1024, 256, 0, stream>>>(x, wq, wk, wv, wo, xb, wqkvb, wob);

  // fused QKV projection + RoPE epilogue: Q/K -> qr/kr directly, V -> qkvr
  const float qscale = 0.08838834764831845f * 1.4426950408889634f;
  gemm192_rope<<<(B_ * S_ / 256) * (QKVN / 192), 512, 0, stream>>>(
      xb, wqkvb, fc, fs, qr, kr, qkvr, qscale, B_ * S_, QKVN, DIM_);

  // V transpose (reads qkvr V columns)
  vtrans_kernel<<<B_ * NKV * (S_ / 128), 256, 0, stream>>>(qkvr + 2560, vtb, QKVN);

  // attention: 256 blocks x 512 thr; uniform 17-tile chains per wave (k-split + pair)
  attn_kernel<<<B_ * NH * 8, 512, 0, stream>>>(qr, kr, vtb, obf);

  // output projection -> f32 d_out (2-phase 256x128 tiles, 256 blocks = 1/CU)
  gemmOP<float><<<(B_ * S_ / 256) * (DIM_ / 128), 512, 0, stream>>>(obf, wob, out, B_ * S_, DIM_, DIM_);
}